// Round 1
// baseline (3112.199 us; speedup 1.0000x reference)
//
#include <hip/hip_runtime.h>

#define BEPS 1e-5f

// ---------------- conv (stride 2, VALID, 3x3) + bias + relu ----------------
__global__ void conv_relu(const float* __restrict__ in, const float* __restrict__ w,
                          const float* __restrict__ effb, float* __restrict__ out,
                          int B, int Ci, int Hi, int Wi, int Co, int Ho, int Wo) {
    int idx = blockIdx.x * blockDim.x + threadIdx.x;
    int total = B * Co * Ho * Wo;
    if (idx >= total) return;
    int j = idx % Wo;
    int t = idx / Wo;
    int i = t % Ho; t /= Ho;
    int co = t % Co;
    int b = t / Co;
    const float* wrow = w + (long long)co * Ci * 9;
    float acc = effb[co];
    const float* ib = in + ((long long)b * Ci) * Hi * Wi + (2 * i) * Wi + 2 * j;
    for (int ci = 0; ci < Ci; ++ci) {
        const float* ip = ib + (long long)ci * Hi * Wi;
        const float* wp = wrow + ci * 9;
#pragma unroll
        for (int di = 0; di < 3; ++di) {
            float x0 = ip[di * Wi + 0];
            float x1 = ip[di * Wi + 1];
            float x2 = ip[di * Wi + 2];
            acc = fmaf(x0, wp[di * 3 + 0], acc);
            acc = fmaf(x1, wp[di * 3 + 1], acc);
            acc = fmaf(x2, wp[di * 3 + 2], acc);
        }
    }
    out[idx] = fmaxf(acc, 0.0f);
}

// ---------------- BN stats: partial sums per (channel, slice) ----------------
__global__ void stats_partial(const float* __restrict__ y, float* __restrict__ part,
                              int B, int C, int HW, int S) {
    int c = blockIdx.x;
    int s = blockIdx.y;
    int tid = threadIdx.x;
    float sum = 0.f, sq = 0.f;
    for (int b = 0; b < B; ++b) {
        const float* yp = y + ((long long)b * C + c) * HW;
        for (int p = s * blockDim.x + tid; p < HW; p += S * blockDim.x) {
            float v = yp[p];
            sum += v;
            sq = fmaf(v, v, sq);
        }
    }
    __shared__ float ls[256], lq[256];
    ls[tid] = sum; lq[tid] = sq;
    __syncthreads();
    for (int o = 128; o > 0; o >>= 1) {
        if (tid < o) { ls[tid] += ls[tid + o]; lq[tid] += lq[tid + o]; }
        __syncthreads();
    }
    if (tid == 0) {
        part[(c * S + s) * 2 + 0] = ls[0];
        part[(c * S + s) * 2 + 1] = lq[0];
    }
}

__global__ void stats_final(const float* __restrict__ part, const float* __restrict__ g,
                            const float* __restrict__ be, float* __restrict__ scale,
                            float* __restrict__ shift, int C, int S, float invN) {
    int c = blockIdx.x * blockDim.x + threadIdx.x;
    if (c >= C) return;
    float s = 0.f, q = 0.f;
    for (int i = 0; i < S; ++i) {
        s += part[(c * S + i) * 2 + 0];
        q += part[(c * S + i) * 2 + 1];
    }
    float m = s * invN;
    float v = q * invN - m * m;
    float inv = rsqrtf(v + BEPS);
    float sc = g[c] * inv;
    scale[c] = sc;
    shift[c] = be[c] - m * sc;
}

// ---------------- fold BN affine of the INPUT into next conv's weights ------
__global__ void fold_w(const float* __restrict__ w, const float* __restrict__ scale,
                       float* __restrict__ wout, int Ci, int total) {
    int idx = blockIdx.x * blockDim.x + threadIdx.x;
    if (idx >= total) return;
    int ci = (idx / 9) % Ci;
    wout[idx] = w[idx] * scale[ci];
}

__global__ void fold_b(const float* __restrict__ w, const float* __restrict__ shift,
                       const float* __restrict__ bias, float* __restrict__ effb,
                       int Co, int Ci) {
    int co = blockIdx.x * blockDim.x + threadIdx.x;
    if (co >= Co) return;
    float acc = bias[co];
    const float* wr = w + (long long)co * Ci * 9;
    for (int ci = 0; ci < Ci; ++ci) {
        float sh = shift[ci];
#pragma unroll
        for (int t = 0; t < 9; ++t) acc = fmaf(wr[ci * 9 + t], sh, acc);
    }
    effb[co] = acc;
}

// ---------------- apply BN affine elementwise (for the FC input) ------------
__global__ void bn_apply(const float* __restrict__ y, const float* __restrict__ scale,
                         const float* __restrict__ shift, float* __restrict__ x,
                         int total, int K, int perc) {
    int idx = blockIdx.x * blockDim.x + threadIdx.x;
    if (idx >= total) return;
    int k = idx % K;
    int c = k / perc;
    x[idx] = fmaf(y[idx], scale[c], shift[c]);
}

// ---------------- fc1: z = relu(x @ w^T + b), x (32,K), w (N,K) -------------
__global__ void fc1(const float* __restrict__ x, const float* __restrict__ w,
                    const float* __restrict__ bias, float* __restrict__ z,
                    int K, int N) {
    int o = blockIdx.x;
    int tid = threadIdx.x;
    float acc[32];
#pragma unroll
    for (int b = 0; b < 32; ++b) acc[b] = 0.f;
    const float* wr = w + (long long)o * K;
    for (int k = tid; k < K; k += blockDim.x) {
        float wv = wr[k];
#pragma unroll
        for (int b = 0; b < 32; ++b) acc[b] = fmaf(x[b * K + k], wv, acc[b]);
    }
    __shared__ float red[256];
    for (int b = 0; b < 32; ++b) {
        red[tid] = acc[b];
        __syncthreads();
        for (int o2 = 128; o2 > 0; o2 >>= 1) {
            if (tid < o2) red[tid] += red[tid + o2];
            __syncthreads();
        }
        if (tid == 0) z[b * N + o] = fmaxf(red[0] + bias[o], 0.f);
        __syncthreads();
    }
}

// ---------------- fc2: ys = z @ w^T + b, z (32,K), w (N,K) ------------------
__global__ void fc2(const float* __restrict__ z, const float* __restrict__ w,
                    const float* __restrict__ bias, float* __restrict__ ys,
                    int B, int K, int N) {
    int idx = blockIdx.x * blockDim.x + threadIdx.x;
    if (idx >= B * N) return;
    int o = idx % N;
    int b = idx / N;
    float acc = bias[o];
    const float* wr = w + (long long)o * K;
    const float* zr = z + (long long)b * K;
    for (int k = 0; k < K; ++k) acc = fmaf(zr[k], wr[k], acc);
    ys[idx] = acc;
}

// ---------------- spline coefficients: 96 rows (b,c) ------------------------
__global__ void spline_coeff(const float* __restrict__ ysraw, const float* __restrict__ matrix,
                             float* __restrict__ Ac, float* __restrict__ Bc,
                             float* __restrict__ Cc, float* __restrict__ Dc) {
    int r = threadIdx.x;
    if (r >= 96) return;
    const float h = 1.0f / 9.0f;
    float ya[10];
    int b = r / 3, ch = r % 3;
#pragma unroll
    for (int j = 0; j < 10; ++j)
        ya[j] = ysraw[b * 30 + ch * 10 + j] / 100.0f + (float)j / 9.0f;
    float M[10];
#pragma unroll
    for (int i = 0; i < 10; ++i) {
        float acc = 0.f;
#pragma unroll
        for (int j = 0; j < 10; ++j) acc = fmaf(matrix[i * 10 + j], ya[j], acc);
        M[i] = acc;
    }
#pragma unroll
    for (int k = 0; k < 9; ++k) {
        Ac[r * 9 + k] = (M[k + 1] - M[k]) / (6.0f * h);
        Bc[r * 9 + k] = M[k] * 0.5f;
        Cc[r * 9 + k] = (ya[k + 1] - ya[k]) / h - (M[k + 1] + 2.0f * M[k]) * (h / 6.0f);
        Dc[r * 9 + k] = ya[k];
    }
}

// ---------------- spline eval on the image ----------------------------------
__global__ void eval_img(const float* __restrict__ batch, const float* __restrict__ Ac,
                         const float* __restrict__ Bc, const float* __restrict__ Cc,
                         const float* __restrict__ Dc, float* __restrict__ out,
                         int total, int HW) {
    int idx = blockIdx.x * blockDim.x + threadIdx.x;
    if (idx >= total) return;
    int plane = idx / HW; // b*3+c
    float xv = batch[idx];
    const float h = 1.0f / 9.0f;
    int xi = (int)floorf(xv / h);
    xi = min(max(xi, 0), 8);
    float xf = xv - (float)xi * h;
    int ci = plane * 9 + xi;
    float a = Ac[ci], bb = Bc[ci], cc = Cc[ci], dd = Dc[ci];
    out[idx] = fmaf(fmaf(fmaf(a, xf, bb), xf, cc), xf, dd);
}

// ---------------- spline eval on the 255-value table ------------------------
__global__ void eval_tab(const float* __restrict__ Ac, const float* __restrict__ Bc,
                         const float* __restrict__ Cc, const float* __restrict__ Dc,
                         float* __restrict__ out, int total) {
    int idx = blockIdx.x * blockDim.x + threadIdx.x;
    if (idx >= total) return;
    int plane = idx / 255;
    int j = idx % 255;
    float xv = (float)j / 255.0f;
    const float h = 1.0f / 9.0f;
    int xi = (int)floorf(xv / h);
    xi = min(max(xi, 0), 8);
    float xf = xv - (float)xi * h;
    int ci = plane * 9 + xi;
    float a = Ac[ci], bb = Bc[ci], cc = Cc[ci], dd = Dc[ci];
    out[idx] = fmaf(fmaf(fmaf(a, xf, bb), xf, cc), xf, dd);
}

extern "C" void kernel_launch(void* const* d_in, const int* in_sizes, int n_in,
                              void* d_out, int out_size, void* d_ws, size_t ws_size,
                              hipStream_t stream) {
    const int B = 32;
    const float* batch = (const float*)d_in[0];
    const float* cw[5] = {(const float*)d_in[1], (const float*)d_in[5], (const float*)d_in[9],
                          (const float*)d_in[13], (const float*)d_in[17]};
    const float* cb[5] = {(const float*)d_in[2], (const float*)d_in[6], (const float*)d_in[10],
                          (const float*)d_in[14], (const float*)d_in[18]};
    const float* bg[5] = {(const float*)d_in[3], (const float*)d_in[7], (const float*)d_in[11],
                          (const float*)d_in[15], (const float*)d_in[19]};
    const float* bb[5] = {(const float*)d_in[4], (const float*)d_in[8], (const float*)d_in[12],
                          (const float*)d_in[16], (const float*)d_in[20]};
    const float* l1w = (const float*)d_in[21];
    const float* l1b = (const float*)d_in[22];
    const float* l2w = (const float*)d_in[23];
    const float* l2b = (const float*)d_in[24];
    const float* matrix = (const float*)d_in[25];

    float* ws = (float*)d_ws;
    // workspace layout (floats)
    float* bufA  = ws;                       // 16,516,096 (y1/y3/y5)
    float* bufB  = bufA + 16516096;          // 8,128,512  (y2/y4)
    float* Wf    = bufB + 8128512;           // 1,179,648  (folded weights)
    float* effb  = Wf + 1179648;             // 512
    float* scale = effb + 512;               // 512
    float* shift = scale + 512;              // 512
    float* part  = shift + 512;              // 8192
    float* x5    = part + 8192;              // 802,816
    float* z1    = x5 + 802816;              // 32,000
    float* ysb   = z1 + 32000;               // 960
    float* ca    = ysb + 960;                // 864
    float* cbuf  = ca + 864;                 // 864
    float* cc    = cbuf + 864;               // 864
    float* cd    = cc + 864;                 // 864

    const int Ci[5] = {3, 32, 64, 128, 256};
    const int Co[5] = {32, 64, 128, 256, 512};
    const int Hi[5] = {256, 127, 63, 31, 15};
    const int Ho[5] = {127, 63, 31, 15, 7};
    const int S = 8;

    const float* cur = batch;
    float* bufs[2] = {bufA, bufB};
    for (int l = 0; l < 5; ++l) {
        float* outb = bufs[l % 2];
        const float* wuse;
        const float* buse;
        if (l == 0) {
            wuse = cw[0];
            buse = cb[0];
        } else {
            int wtotal = Co[l] * Ci[l] * 9;
            fold_w<<<(wtotal + 255) / 256, 256, 0, stream>>>(cw[l], scale, Wf, Ci[l], wtotal);
            fold_b<<<(Co[l] + 63) / 64, 64, 0, stream>>>(cw[l], shift, cb[l], effb, Co[l], Ci[l]);
            wuse = Wf;
            buse = effb;
        }
        int total = B * Co[l] * Ho[l] * Ho[l];
        conv_relu<<<(total + 255) / 256, 256, 0, stream>>>(cur, wuse, buse, outb, B, Ci[l],
                                                           Hi[l], Hi[l], Co[l], Ho[l], Ho[l]);
        stats_partial<<<dim3(Co[l], S), 256, 0, stream>>>(outb, part, B, Co[l], Ho[l] * Ho[l], S);
        stats_final<<<(Co[l] + 63) / 64, 64, 0, stream>>>(part, bg[l], bb[l], scale, shift,
                                                          Co[l], S, 1.0f / (B * Ho[l] * Ho[l]));
        cur = outb;
    }

    // BN-apply on conv5 output -> fc input
    bn_apply<<<(802816 + 255) / 256, 256, 0, stream>>>(cur, scale, shift, x5, 802816, 25088, 49);
    fc1<<<1000, 256, 0, stream>>>(x5, l1w, l1b, z1, 25088, 1000);
    fc2<<<(960 + 255) / 256, 256, 0, stream>>>(z1, l2w, l2b, ysb, B, 1000, 30);
    spline_coeff<<<1, 96, 0, stream>>>(ysb, matrix, ca, cbuf, cc, cd);

    float* out = (float*)d_out;
    eval_img<<<(6291456 + 255) / 256, 256, 0, stream>>>(batch, ca, cbuf, cc, cd, out,
                                                        6291456, 65536);
    eval_tab<<<(96 * 255 + 255) / 256, 256, 0, stream>>>(ca, cbuf, cc, cd, out + 6291456,
                                                         96 * 255);
}

// Round 2
// 1640.461 us; speedup vs baseline: 1.8971x; 1.8971x over previous
//
#include <hip/hip_runtime.h>

#define BEPS 1e-5f

// ---------------- implicit-GEMM conv (stride 2, VALID, 3x3) + bias + relu ----
// C[Co][B*Ho*Wo] = W[Co][Ci*9] @ im2col(in), tiles 64x64x16, 256 thr, 4x4 regs
__global__ __launch_bounds__(256) void conv_gemm(
    const float* __restrict__ in, const float* __restrict__ w,
    const float* __restrict__ effb, float* __restrict__ out,
    int B, int Ci, int Hi, int Wi, int Co, int Ho, int Wo) {
    const int HoWo = Ho * Wo;
    const int N = B * HoWo;
    const int K = Ci * 9;
    const int HiWi = Hi * Wi;
    __shared__ __align__(16) float As[16][64];   // [kk][mm]
    __shared__ __align__(16) float Bs[16][64];   // [kk][nn]
    const int tid = threadIdx.x;
    const int m0 = blockIdx.y * 64;
    const int n0 = blockIdx.x * 64;
    const int tm = tid >> 4;   // 0..15
    const int tn = tid & 15;   // 0..15

    // per-thread pixel coords for the 4 N-columns this thread owns (stage+epilogue)
    int nb[4], npp[4];
    long long base[4];
    bool nv[4];
#pragma unroll
    for (int e = 0; e < 4; ++e) {
        int n = n0 + tn * 4 + e;
        nv[e] = (n < N);
        int nn = nv[e] ? n : 0;
        int b = nn / HoWo, p = nn - b * HoWo;
        int i = p / Wo, j = p - i * Wo;
        nb[e] = b; npp[e] = p;
        base[e] = (long long)b * Ci * HiWi + (2 * i) * Wi + 2 * j;
    }
    const int cA = tid >> 2;   // 0..63: co within tile (A staging)
    const int kqA = tid & 3;   // 0..3
    const int kkB = tid >> 4;  // 0..15: k row (B staging)

    float acc[4][4] = {};
    for (int k0 = 0; k0 < K; k0 += 16) {
        // stage A (weights)
#pragma unroll
        for (int e = 0; e < 4; ++e) {
            int k = k0 + kqA * 4 + e;
            int m = m0 + cA;
            As[kqA * 4 + e][cA] = (m < Co && k < K) ? w[(long long)m * K + k] : 0.f;
        }
        // stage B (im2col patches)
        {
            int k = k0 + kkB;
            float v[4] = {0.f, 0.f, 0.f, 0.f};
            if (k < K) {
                int ci = k / 9, r = k - ci * 9;
                int dy = r / 3, dx = r - dy * 3;
                long long off = (long long)ci * HiWi + dy * Wi + dx;
#pragma unroll
                for (int e = 0; e < 4; ++e)
                    if (nv[e]) v[e] = in[base[e] + off];
            }
#pragma unroll
            for (int e = 0; e < 4; ++e) Bs[kkB][tn * 4 + e] = v[e];
        }
        __syncthreads();
#pragma unroll
        for (int kk = 0; kk < 16; ++kk) {
            float4 av = *(const float4*)&As[kk][tm * 4];
            float4 bv = *(const float4*)&Bs[kk][tn * 4];
            float a4[4] = {av.x, av.y, av.z, av.w};
            float b4[4] = {bv.x, bv.y, bv.z, bv.w};
#pragma unroll
            for (int mi = 0; mi < 4; ++mi)
#pragma unroll
                for (int ni = 0; ni < 4; ++ni)
                    acc[mi][ni] = fmaf(a4[mi], b4[ni], acc[mi][ni]);
        }
        __syncthreads();
    }
    // epilogue: bias + relu, write NCHW
#pragma unroll
    for (int mi = 0; mi < 4; ++mi) {
        int m = m0 + tm * 4 + mi;
        if (m >= Co) continue;
        float bias = effb[m];
#pragma unroll
        for (int e = 0; e < 4; ++e) {
            if (!nv[e]) continue;
            out[((long long)nb[e] * Co + m) * HoWo + npp[e]] = fmaxf(acc[mi][e] + bias, 0.f);
        }
    }
}

// ---------------- BN stats: partial sums per (channel, slice) ----------------
__global__ void stats_partial(const float* __restrict__ y, float* __restrict__ part,
                              int B, int C, int HW, int S) {
    int c = blockIdx.x;
    int s = blockIdx.y;
    int tid = threadIdx.x;
    float sum = 0.f, sq = 0.f;
    for (int b = 0; b < B; ++b) {
        const float* yp = y + ((long long)b * C + c) * HW;
        for (int p = s * blockDim.x + tid; p < HW; p += S * blockDim.x) {
            float v = yp[p];
            sum += v;
            sq = fmaf(v, v, sq);
        }
    }
    __shared__ float ls[256], lq[256];
    ls[tid] = sum; lq[tid] = sq;
    __syncthreads();
    for (int o = 128; o > 0; o >>= 1) {
        if (tid < o) { ls[tid] += ls[tid + o]; lq[tid] += lq[tid + o]; }
        __syncthreads();
    }
    if (tid == 0) {
        part[(c * S + s) * 2 + 0] = ls[0];
        part[(c * S + s) * 2 + 1] = lq[0];
    }
}

__global__ void stats_final(const float* __restrict__ part, const float* __restrict__ g,
                            const float* __restrict__ be, float* __restrict__ scale,
                            float* __restrict__ shift, int C, int S, float invN) {
    int c = blockIdx.x * blockDim.x + threadIdx.x;
    if (c >= C) return;
    float s = 0.f, q = 0.f;
    for (int i = 0; i < S; ++i) {
        s += part[(c * S + i) * 2 + 0];
        q += part[(c * S + i) * 2 + 1];
    }
    float m = s * invN;
    float v = q * invN - m * m;
    float inv = rsqrtf(v + BEPS);
    float sc = g[c] * inv;
    scale[c] = sc;
    shift[c] = be[c] - m * sc;
}

// ---------------- fold BN affine of the INPUT into next conv's weights ------
__global__ void fold_w(const float* __restrict__ w, const float* __restrict__ scale,
                       float* __restrict__ wout, int Ci, int total) {
    int idx = blockIdx.x * blockDim.x + threadIdx.x;
    if (idx >= total) return;
    int ci = (idx / 9) % Ci;
    wout[idx] = w[idx] * scale[ci];
}

__global__ void fold_b(const float* __restrict__ w, const float* __restrict__ shift,
                       const float* __restrict__ bias, float* __restrict__ effb,
                       int Co, int Ci) {
    int co = blockIdx.x * blockDim.x + threadIdx.x;
    if (co >= Co) return;
    float acc = bias[co];
    const float* wr = w + (long long)co * Ci * 9;
    for (int ci = 0; ci < Ci; ++ci) {
        float sh = shift[ci];
#pragma unroll
        for (int t = 0; t < 9; ++t) acc = fmaf(wr[ci * 9 + t], sh, acc);
    }
    effb[co] = acc;
}

// ---------------- apply BN affine elementwise (for the FC input) ------------
__global__ void bn_apply(const float* __restrict__ y, const float* __restrict__ scale,
                         const float* __restrict__ shift, float* __restrict__ x,
                         int total, int K, int perc) {
    int idx = blockIdx.x * blockDim.x + threadIdx.x;
    if (idx >= total) return;
    int k = idx % K;
    int c = k / perc;
    x[idx] = fmaf(y[idx], scale[c], shift[c]);
}

// ---------------- fc1: z = relu(x @ w^T + b); 4 outputs per block ----------
__global__ __launch_bounds__(256) void fc1_v2(const float* __restrict__ x,
                                              const float* __restrict__ w,
                                              const float* __restrict__ bias,
                                              float* __restrict__ z, int K, int N) {
    int o0 = blockIdx.x * 4;
    int tid = threadIdx.x;
    float acc[4][32];
#pragma unroll
    for (int o = 0; o < 4; ++o)
#pragma unroll
        for (int b = 0; b < 32; ++b) acc[o][b] = 0.f;

    const float* w0 = w + (long long)(o0 + 0) * K;
    const float* w1 = w + (long long)(o0 + 1) * K;
    const float* w2 = w + (long long)(o0 + 2) * K;
    const float* w3 = w + (long long)(o0 + 3) * K;
    for (int k = tid; k < K; k += 256) {
        float wa = w0[k], wb = w1[k], wc = w2[k], wd = w3[k];
#pragma unroll
        for (int b = 0; b < 32; ++b) {
            float xv = x[b * K + k];
            acc[0][b] = fmaf(xv, wa, acc[0][b]);
            acc[1][b] = fmaf(xv, wb, acc[1][b]);
            acc[2][b] = fmaf(xv, wc, acc[2][b]);
            acc[3][b] = fmaf(xv, wd, acc[3][b]);
        }
    }
    __shared__ float part[4][4][32];  // [wave][o][b]
    int lane = tid & 63, wv = tid >> 6;
#pragma unroll
    for (int o = 0; o < 4; ++o) {
#pragma unroll
        for (int b = 0; b < 32; ++b) {
            float v = acc[o][b];
            for (int off = 32; off > 0; off >>= 1) v += __shfl_down(v, off, 64);
            if (lane == 0) part[wv][o][b] = v;
        }
    }
    __syncthreads();
    if (tid < 128) {
        int o = tid >> 5, b = tid & 31;
        float s = part[0][o][b] + part[1][o][b] + part[2][o][b] + part[3][o][b];
        z[b * N + o0 + o] = fmaxf(s + bias[o0 + o], 0.f);
    }
}

// ---------------- fc2: ys = z @ w^T + b ------------------------------------
__global__ void fc2(const float* __restrict__ z, const float* __restrict__ w,
                    const float* __restrict__ bias, float* __restrict__ ys,
                    int B, int K, int N) {
    int idx = blockIdx.x * blockDim.x + threadIdx.x;
    if (idx >= B * N) return;
    int o = idx % N;
    int b = idx / N;
    float acc = bias[o];
    const float* wr = w + (long long)o * K;
    const float* zr = z + (long long)b * K;
    for (int k = 0; k < K; ++k) acc = fmaf(zr[k], wr[k], acc);
    ys[idx] = acc;
}

// ---------------- spline coefficients: 96 rows (b,c) ------------------------
__global__ void spline_coeff(const float* __restrict__ ysraw, const float* __restrict__ matrix,
                             float* __restrict__ Ac, float* __restrict__ Bc,
                             float* __restrict__ Cc, float* __restrict__ Dc) {
    int r = threadIdx.x;
    if (r >= 96) return;
    const float h = 1.0f / 9.0f;
    float ya[10];
    int b = r / 3, ch = r % 3;
#pragma unroll
    for (int j = 0; j < 10; ++j)
        ya[j] = ysraw[b * 30 + ch * 10 + j] / 100.0f + (float)j / 9.0f;
    float M[10];
#pragma unroll
    for (int i = 0; i < 10; ++i) {
        float acc = 0.f;
#pragma unroll
        for (int j = 0; j < 10; ++j) acc = fmaf(matrix[i * 10 + j], ya[j], acc);
        M[i] = acc;
    }
#pragma unroll
    for (int k = 0; k < 9; ++k) {
        Ac[r * 9 + k] = (M[k + 1] - M[k]) / (6.0f * h);
        Bc[r * 9 + k] = M[k] * 0.5f;
        Cc[r * 9 + k] = (ya[k + 1] - ya[k]) / h - (M[k + 1] + 2.0f * M[k]) * (h / 6.0f);
        Dc[r * 9 + k] = ya[k];
    }
}

// ---------------- spline eval on the image ----------------------------------
__global__ void eval_img(const float* __restrict__ batch, const float* __restrict__ Ac,
                         const float* __restrict__ Bc, const float* __restrict__ Cc,
                         const float* __restrict__ Dc, float* __restrict__ out,
                         int total, int HW) {
    int idx = blockIdx.x * blockDim.x + threadIdx.x;
    if (idx >= total) return;
    int plane = idx / HW; // b*3+c
    float xv = batch[idx];
    const float h = 1.0f / 9.0f;
    int xi = (int)floorf(xv / h);
    xi = min(max(xi, 0), 8);
    float xf = xv - (float)xi * h;
    int ci = plane * 9 + xi;
    float a = Ac[ci], bb = Bc[ci], cc = Cc[ci], dd = Dc[ci];
    out[idx] = fmaf(fmaf(fmaf(a, xf, bb), xf, cc), xf, dd);
}

// ---------------- spline eval on the 255-value table ------------------------
__global__ void eval_tab(const float* __restrict__ Ac, const float* __restrict__ Bc,
                         const float* __restrict__ Cc, const float* __restrict__ Dc,
                         float* __restrict__ out, int total) {
    int idx = blockIdx.x * blockDim.x + threadIdx.x;
    if (idx >= total) return;
    int plane = idx / 255;
    int j = idx % 255;
    float xv = (float)j / 255.0f;
    const float h = 1.0f / 9.0f;
    int xi = (int)floorf(xv / h);
    xi = min(max(xi, 0), 8);
    float xf = xv - (float)xi * h;
    int ci = plane * 9 + xi;
    float a = Ac[ci], bb = Bc[ci], cc = Cc[ci], dd = Dc[ci];
    out[idx] = fmaf(fmaf(fmaf(a, xf, bb), xf, cc), xf, dd);
}

extern "C" void kernel_launch(void* const* d_in, const int* in_sizes, int n_in,
                              void* d_out, int out_size, void* d_ws, size_t ws_size,
                              hipStream_t stream) {
    const int B = 32;
    const float* batch = (const float*)d_in[0];
    const float* cw[5] = {(const float*)d_in[1], (const float*)d_in[5], (const float*)d_in[9],
                          (const float*)d_in[13], (const float*)d_in[17]};
    const float* cb[5] = {(const float*)d_in[2], (const float*)d_in[6], (const float*)d_in[10],
                          (const float*)d_in[14], (const float*)d_in[18]};
    const float* bg[5] = {(const float*)d_in[3], (const float*)d_in[7], (const float*)d_in[11],
                          (const float*)d_in[15], (const float*)d_in[19]};
    const float* bb[5] = {(const float*)d_in[4], (const float*)d_in[8], (const float*)d_in[12],
                          (const float*)d_in[16], (const float*)d_in[20]};
    const float* l1w = (const float*)d_in[21];
    const float* l1b = (const float*)d_in[22];
    const float* l2w = (const float*)d_in[23];
    const float* l2b = (const float*)d_in[24];
    const float* matrix = (const float*)d_in[25];

    float* ws = (float*)d_ws;
    float* bufA  = ws;                       // 16,516,096
    float* bufB  = bufA + 16516096;          // 8,128,512
    float* Wf    = bufB + 8128512;           // 1,179,648
    float* effb  = Wf + 1179648;             // 512
    float* scale = effb + 512;               // 512
    float* shift = scale + 512;              // 512
    float* part  = shift + 512;              // 8192
    float* x5    = part + 8192;              // 802,816
    float* z1    = x5 + 802816;              // 32,000
    float* ysb   = z1 + 32000;               // 960
    float* ca    = ysb + 960;                // 864
    float* cbuf  = ca + 864;                 // 864
    float* cc    = cbuf + 864;               // 864
    float* cd    = cc + 864;                 // 864

    const int Ci[5] = {3, 32, 64, 128, 256};
    const int Co[5] = {32, 64, 128, 256, 512};
    const int Hi[5] = {256, 127, 63, 31, 15};
    const int Ho[5] = {127, 63, 31, 15, 7};
    const int S = 8;

    const float* cur = batch;
    float* bufs[2] = {bufA, bufB};
    for (int l = 0; l < 5; ++l) {
        float* outb = bufs[l % 2];
        const float* wuse;
        const float* buse;
        if (l == 0) {
            wuse = cw[0];
            buse = cb[0];
        } else {
            int wtotal = Co[l] * Ci[l] * 9;
            fold_w<<<(wtotal + 255) / 256, 256, 0, stream>>>(cw[l], scale, Wf, Ci[l], wtotal);
            fold_b<<<(Co[l] + 63) / 64, 64, 0, stream>>>(cw[l], shift, cb[l], effb, Co[l], Ci[l]);
            wuse = Wf;
            buse = effb;
        }
        int N = B * Ho[l] * Ho[l];
        dim3 grid((N + 63) / 64, (Co[l] + 63) / 64);
        conv_gemm<<<grid, 256, 0, stream>>>(cur, wuse, buse, outb, B, Ci[l],
                                            Hi[l], Hi[l], Co[l], Ho[l], Ho[l]);
        stats_partial<<<dim3(Co[l], S), 256, 0, stream>>>(outb, part, B, Co[l], Ho[l] * Ho[l], S);
        stats_final<<<(Co[l] + 63) / 64, 64, 0, stream>>>(part, bg[l], bb[l], scale, shift,
                                                          Co[l], S, 1.0f / (B * Ho[l] * Ho[l]));
        cur = outb;
    }

    bn_apply<<<(802816 + 255) / 256, 256, 0, stream>>>(cur, scale, shift, x5, 802816, 25088, 49);
    fc1_v2<<<250, 256, 0, stream>>>(x5, l1w, l1b, z1, 25088, 1000);
    fc2<<<(960 + 255) / 256, 256, 0, stream>>>(z1, l2w, l2b, ysb, B, 1000, 30);
    spline_coeff<<<1, 96, 0, stream>>>(ysb, matrix, ca, cbuf, cc, cd);

    float* out = (float*)d_out;
    eval_img<<<(6291456 + 255) / 256, 256, 0, stream>>>(batch, ca, cbuf, cc, cd, out,
                                                        6291456, 65536);
    eval_tab<<<(96 * 255 + 255) / 256, 256, 0, stream>>>(ca, cbuf, cc, cd, out + 6291456,
                                                         96 * 255);
}

// Round 3
// 1125.609 us; speedup vs baseline: 2.7649x; 1.4574x over previous
//
#include <hip/hip_runtime.h>

#define BEPS 1e-5f
#define FC1_KS 98
#define FC1_KC 256

// ---------------- implicit-GEMM conv (stride 2, VALID, 3x3) + bias + relu ----
__global__ __launch_bounds__(256) void conv_gemm(
    const float* __restrict__ in, const float* __restrict__ w,
    const float* __restrict__ effb, float* __restrict__ out,
    int B, int Ci, int Hi, int Wi, int Co, int Ho, int Wo) {
    const int HoWo = Ho * Wo;
    const int N = B * HoWo;
    const int K = Ci * 9;
    const int HiWi = Hi * Wi;
    __shared__ __align__(16) float As[16][64];   // [kk][mm]
    __shared__ __align__(16) float Bs[16][64];   // [kk][nn]
    const int tid = threadIdx.x;
    const int m0 = blockIdx.y * 64;
    const int n0 = blockIdx.x * 64;
    const int tm = tid >> 4;
    const int tn = tid & 15;

    int nb[4], npp[4];
    long long base[4];
    bool nv[4];
#pragma unroll
    for (int e = 0; e < 4; ++e) {
        int n = n0 + tn * 4 + e;
        nv[e] = (n < N);
        int nn = nv[e] ? n : 0;
        int b = nn / HoWo, p = nn - b * HoWo;
        int i = p / Wo, j = p - i * Wo;
        nb[e] = b; npp[e] = p;
        base[e] = (long long)b * Ci * HiWi + (2 * i) * Wi + 2 * j;
    }
    const int cA = tid >> 2;
    const int kqA = tid & 3;
    const int kkB = tid >> 4;

    float acc[4][4] = {};
    for (int k0 = 0; k0 < K; k0 += 16) {
#pragma unroll
        for (int e = 0; e < 4; ++e) {
            int k = k0 + kqA * 4 + e;
            int m = m0 + cA;
            As[kqA * 4 + e][cA] = (m < Co && k < K) ? w[(long long)m * K + k] : 0.f;
        }
        {
            int k = k0 + kkB;
            float v[4] = {0.f, 0.f, 0.f, 0.f};
            if (k < K) {
                int ci = k / 9, r = k - ci * 9;
                int dy = r / 3, dx = r - dy * 3;
                long long off = (long long)ci * HiWi + dy * Wi + dx;
#pragma unroll
                for (int e = 0; e < 4; ++e)
                    if (nv[e]) v[e] = in[base[e] + off];
            }
#pragma unroll
            for (int e = 0; e < 4; ++e) Bs[kkB][tn * 4 + e] = v[e];
        }
        __syncthreads();
#pragma unroll
        for (int kk = 0; kk < 16; ++kk) {
            float4 av = *(const float4*)&As[kk][tm * 4];
            float4 bv = *(const float4*)&Bs[kk][tn * 4];
            float a4[4] = {av.x, av.y, av.z, av.w};
            float b4[4] = {bv.x, bv.y, bv.z, bv.w};
#pragma unroll
            for (int mi = 0; mi < 4; ++mi)
#pragma unroll
                for (int ni = 0; ni < 4; ++ni)
                    acc[mi][ni] = fmaf(a4[mi], b4[ni], acc[mi][ni]);
        }
        __syncthreads();
    }
#pragma unroll
    for (int mi = 0; mi < 4; ++mi) {
        int m = m0 + tm * 4 + mi;
        if (m >= Co) continue;
        float bias = effb[m];
#pragma unroll
        for (int e = 0; e < 4; ++e) {
            if (!nv[e]) continue;
            out[((long long)nb[e] * Co + m) * HoWo + npp[e]] = fmaxf(acc[mi][e] + bias, 0.f);
        }
    }
}

// ---------------- BN stats ---------------------------------------------------
__global__ void stats_partial(const float* __restrict__ y, float* __restrict__ part,
                              int B, int C, int HW, int S) {
    int c = blockIdx.x;
    int s = blockIdx.y;
    int tid = threadIdx.x;
    float sum = 0.f, sq = 0.f;
    for (int b = 0; b < B; ++b) {
        const float* yp = y + ((long long)b * C + c) * HW;
        for (int p = s * blockDim.x + tid; p < HW; p += S * blockDim.x) {
            float v = yp[p];
            sum += v;
            sq = fmaf(v, v, sq);
        }
    }
    __shared__ float ls[256], lq[256];
    ls[tid] = sum; lq[tid] = sq;
    __syncthreads();
    for (int o = 128; o > 0; o >>= 1) {
        if (tid < o) { ls[tid] += ls[tid + o]; lq[tid] += lq[tid + o]; }
        __syncthreads();
    }
    if (tid == 0) {
        part[(c * S + s) * 2 + 0] = ls[0];
        part[(c * S + s) * 2 + 1] = lq[0];
    }
}

__global__ void stats_final(const float* __restrict__ part, const float* __restrict__ g,
                            const float* __restrict__ be, float* __restrict__ scale,
                            float* __restrict__ shift, int C, int S, float invN) {
    int c = blockIdx.x * blockDim.x + threadIdx.x;
    if (c >= C) return;
    float s = 0.f, q = 0.f;
    for (int i = 0; i < S; ++i) {
        s += part[(c * S + i) * 2 + 0];
        q += part[(c * S + i) * 2 + 1];
    }
    float m = s * invN;
    float v = q * invN - m * m;
    float inv = rsqrtf(v + BEPS);
    float sc = g[c] * inv;
    scale[c] = sc;
    shift[c] = be[c] - m * sc;
}

// ---------------- BN fold into next conv ------------------------------------
__global__ void fold_w(const float* __restrict__ w, const float* __restrict__ scale,
                       float* __restrict__ wout, int Ci, int total) {
    int idx = blockIdx.x * blockDim.x + threadIdx.x;
    if (idx >= total) return;
    int ci = (idx / 9) % Ci;
    wout[idx] = w[idx] * scale[ci];
}

__global__ void fold_b(const float* __restrict__ w, const float* __restrict__ shift,
                       const float* __restrict__ bias, float* __restrict__ effb,
                       int Co, int Ci) {
    int co = blockIdx.x * blockDim.x + threadIdx.x;
    if (co >= Co) return;
    float acc = bias[co];
    const float* wr = w + (long long)co * Ci * 9;
    for (int ci = 0; ci < Ci; ++ci) {
        float sh = shift[ci];
#pragma unroll
        for (int t = 0; t < 9; ++t) acc = fmaf(wr[ci * 9 + t], sh, acc);
    }
    effb[co] = acc;
}

// ---------------- BN apply, writing xT[k][32] (transposed for fc1) ----------
__global__ void bn_apply_t(const float* __restrict__ y, const float* __restrict__ scale,
                           const float* __restrict__ shift, float* __restrict__ xT) {
    int idx = blockIdx.x * blockDim.x + threadIdx.x;
    if (idx >= 802816) return;
    int k = idx >> 5, b = idx & 31;
    int c = k / 49;
    xT[idx] = fmaf(y[(long long)b * 25088 + k], scale[c], shift[c]);
}

// ---------------- fc1 split-K GEMM: partial[mt,ks][64x32] -------------------
__global__ __launch_bounds__(256) void fc1_gemm(const float* __restrict__ xT,
                                                const float* __restrict__ w,
                                                float* __restrict__ part) {
    const int K = 25088;
    __shared__ __align__(16) float As[16][64];
    __shared__ __align__(16) float Bs[16][32];
    const int tid = threadIdx.x;
    const int m0 = blockIdx.y * 64;
    const int kbeg = blockIdx.x * FC1_KC;
    const int cA = tid >> 2;
    const int kqA = (tid & 3) * 4;
    const int kkB = tid >> 5;
    const int bB = tid & 31;
    const int tm = tid >> 4;
    const int tn = tid & 15;

    const int mrow = m0 + cA;
    const bool mvalid = (mrow < 1000);
    const float* wrow = w + (long long)mrow * K + kbeg + kqA;

    float acc[4][2] = {};
    for (int k0 = 0; k0 < FC1_KC; k0 += 16) {
        float4 av = mvalid ? *(const float4*)(wrow + k0)
                           : make_float4(0.f, 0.f, 0.f, 0.f);
        As[kqA + 0][cA] = av.x;
        As[kqA + 1][cA] = av.y;
        As[kqA + 2][cA] = av.z;
        As[kqA + 3][cA] = av.w;
#pragma unroll
        for (int e = 0; e < 2; ++e) {
            int kk = kkB + e * 8;
            Bs[kk][bB] = xT[(kbeg + k0 + kk) * 32 + bB];
        }
        __syncthreads();
#pragma unroll
        for (int kk = 0; kk < 16; ++kk) {
            float4 a = *(const float4*)&As[kk][tm * 4];
            float b0 = Bs[kk][tn * 2 + 0];
            float b1 = Bs[kk][tn * 2 + 1];
            float a4[4] = {a.x, a.y, a.z, a.w};
#pragma unroll
            for (int mi = 0; mi < 4; ++mi) {
                acc[mi][0] = fmaf(a4[mi], b0, acc[mi][0]);
                acc[mi][1] = fmaf(a4[mi], b1, acc[mi][1]);
            }
        }
        __syncthreads();
    }
    float* pb = part + ((long long)blockIdx.y * FC1_KS + blockIdx.x) * 2048;
#pragma unroll
    for (int mi = 0; mi < 4; ++mi) {
        pb[(tm * 4 + mi) * 32 + tn * 2 + 0] = acc[mi][0];
        pb[(tm * 4 + mi) * 32 + tn * 2 + 1] = acc[mi][1];
    }
}

// ---------------- fc1 reduce: sum partials + bias + relu --------------------
__global__ void fc1_reduce(const float* __restrict__ part, const float* __restrict__ bias,
                           float* __restrict__ z) {
    int idx = blockIdx.x * blockDim.x + threadIdx.x;
    if (idx >= 32000) return;
    int o = idx >> 5, b = idx & 31;
    int mt = o >> 6, mr = o & 63;
    const float* p = part + ((long long)mt * FC1_KS) * 2048 + mr * 32 + b;
    float s0 = 0.f, s1 = 0.f;
    int ks = 0;
    for (; ks + 1 < FC1_KS; ks += 2) {
        s0 += p[(long long)ks * 2048];
        s1 += p[(long long)(ks + 1) * 2048];
    }
    for (; ks < FC1_KS; ++ks) s0 += p[(long long)ks * 2048];
    z[b * 1000 + o] = fmaxf(s0 + s1 + bias[o], 0.f);
}

// ---------------- fc2: wave per output --------------------------------------
__global__ __launch_bounds__(256) void fc2_v2(const float* __restrict__ z,
                                              const float* __restrict__ w,
                                              const float* __restrict__ bias,
                                              float* __restrict__ ys) {
    int gid = blockIdx.x * 4 + (threadIdx.x >> 6);
    int lane = threadIdx.x & 63;
    if (gid >= 960) return;
    int b = gid / 30, o = gid - b * 30;
    const float* zr = z + (long long)b * 1000;
    const float* wr = w + (long long)o * 1000;
    float acc = 0.f;
    for (int k = lane; k < 1000; k += 64) acc = fmaf(zr[k], wr[k], acc);
    for (int off = 32; off > 0; off >>= 1) acc += __shfl_down(acc, off, 64);
    if (lane == 0) ys[gid] = acc + bias[o];
}

// ---------------- spline coefficients ---------------------------------------
__global__ void spline_coeff(const float* __restrict__ ysraw, const float* __restrict__ matrix,
                             float* __restrict__ Ac, float* __restrict__ Bc,
                             float* __restrict__ Cc, float* __restrict__ Dc) {
    int r = threadIdx.x;
    if (r >= 96) return;
    const float h = 1.0f / 9.0f;
    float ya[10];
    int b = r / 3, ch = r % 3;
#pragma unroll
    for (int j = 0; j < 10; ++j)
        ya[j] = ysraw[b * 30 + ch * 10 + j] / 100.0f + (float)j / 9.0f;
    float M[10];
#pragma unroll
    for (int i = 0; i < 10; ++i) {
        float acc = 0.f;
#pragma unroll
        for (int j = 0; j < 10; ++j) acc = fmaf(matrix[i * 10 + j], ya[j], acc);
        M[i] = acc;
    }
#pragma unroll
    for (int k = 0; k < 9; ++k) {
        Ac[r * 9 + k] = (M[k + 1] - M[k]) / (6.0f * h);
        Bc[r * 9 + k] = M[k] * 0.5f;
        Cc[r * 9 + k] = (ya[k + 1] - ya[k]) / h - (M[k + 1] + 2.0f * M[k]) * (h / 6.0f);
        Dc[r * 9 + k] = ya[k];
    }
}

// ---------------- spline eval on the image ----------------------------------
__global__ void eval_img(const float* __restrict__ batch, const float* __restrict__ Ac,
                         const float* __restrict__ Bc, const float* __restrict__ Cc,
                         const float* __restrict__ Dc, float* __restrict__ out,
                         int total, int HW) {
    int idx = blockIdx.x * blockDim.x + threadIdx.x;
    if (idx >= total) return;
    int plane = idx / HW;
    float xv = batch[idx];
    const float h = 1.0f / 9.0f;
    int xi = (int)floorf(xv / h);
    xi = min(max(xi, 0), 8);
    float xf = xv - (float)xi * h;
    int ci = plane * 9 + xi;
    float a = Ac[ci], bb = Bc[ci], cc = Cc[ci], dd = Dc[ci];
    out[idx] = fmaf(fmaf(fmaf(a, xf, bb), xf, cc), xf, dd);
}

// ---------------- spline eval on the 255-value table ------------------------
__global__ void eval_tab(const float* __restrict__ Ac, const float* __restrict__ Bc,
                         const float* __restrict__ Cc, const float* __restrict__ Dc,
                         float* __restrict__ out, int total) {
    int idx = blockIdx.x * blockDim.x + threadIdx.x;
    if (idx >= total) return;
    int plane = idx / 255;
    int j = idx % 255;
    float xv = (float)j / 255.0f;
    const float h = 1.0f / 9.0f;
    int xi = (int)floorf(xv / h);
    xi = min(max(xi, 0), 8);
    float xf = xv - (float)xi * h;
    int ci = plane * 9 + xi;
    float a = Ac[ci], bb = Bc[ci], cc = Cc[ci], dd = Dc[ci];
    out[idx] = fmaf(fmaf(fmaf(a, xf, bb), xf, cc), xf, dd);
}

extern "C" void kernel_launch(void* const* d_in, const int* in_sizes, int n_in,
                              void* d_out, int out_size, void* d_ws, size_t ws_size,
                              hipStream_t stream) {
    const int B = 32;
    const float* batch = (const float*)d_in[0];
    const float* cw[5] = {(const float*)d_in[1], (const float*)d_in[5], (const float*)d_in[9],
                          (const float*)d_in[13], (const float*)d_in[17]};
    const float* cb[5] = {(const float*)d_in[2], (const float*)d_in[6], (const float*)d_in[10],
                          (const float*)d_in[14], (const float*)d_in[18]};
    const float* bg[5] = {(const float*)d_in[3], (const float*)d_in[7], (const float*)d_in[11],
                          (const float*)d_in[15], (const float*)d_in[19]};
    const float* bb[5] = {(const float*)d_in[4], (const float*)d_in[8], (const float*)d_in[12],
                          (const float*)d_in[16], (const float*)d_in[20]};
    const float* l1w = (const float*)d_in[21];
    const float* l1b = (const float*)d_in[22];
    const float* l2w = (const float*)d_in[23];
    const float* l2b = (const float*)d_in[24];
    const float* matrix = (const float*)d_in[25];

    float* ws = (float*)d_ws;
    float* bufA  = ws;                       // 16,516,096
    float* bufB  = bufA + 16516096;          // 8,128,512 (reused as fc1 partials)
    float* Wf    = bufB + 8128512;           // 1,179,648
    float* effb  = Wf + 1179648;             // 512
    float* scale = effb + 512;               // 512
    float* shift = scale + 512;              // 512
    float* part  = shift + 512;              // 8192
    float* x5    = part + 8192;              // 802,816 (xT)
    float* z1    = x5 + 802816;              // 32,000
    float* ysb   = z1 + 32000;               // 960
    float* ca    = ysb + 960;                // 864
    float* cbuf  = ca + 864;                 // 864
    float* cc    = cbuf + 864;               // 864
    float* cd    = cc + 864;                 // 864

    const int Ci[5] = {3, 32, 64, 128, 256};
    const int Co[5] = {32, 64, 128, 256, 512};
    const int Hi[5] = {256, 127, 63, 31, 15};
    const int Ho[5] = {127, 63, 31, 15, 7};
    const int S = 8;

    const float* cur = batch;
    float* bufs[2] = {bufA, bufB};
    for (int l = 0; l < 5; ++l) {
        float* outb = bufs[l % 2];
        const float* wuse;
        const float* buse;
        if (l == 0) {
            wuse = cw[0];
            buse = cb[0];
        } else {
            int wtotal = Co[l] * Ci[l] * 9;
            fold_w<<<(wtotal + 255) / 256, 256, 0, stream>>>(cw[l], scale, Wf, Ci[l], wtotal);
            fold_b<<<(Co[l] + 63) / 64, 64, 0, stream>>>(cw[l], shift, cb[l], effb, Co[l], Ci[l]);
            wuse = Wf;
            buse = effb;
        }
        int N = B * Ho[l] * Ho[l];
        dim3 grid((N + 63) / 64, (Co[l] + 63) / 64);
        conv_gemm<<<grid, 256, 0, stream>>>(cur, wuse, buse, outb, B, Ci[l],
                                            Hi[l], Hi[l], Co[l], Ho[l], Ho[l]);
        stats_partial<<<dim3(Co[l], S), 256, 0, stream>>>(outb, part, B, Co[l], Ho[l] * Ho[l], S);
        stats_final<<<(Co[l] + 63) / 64, 64, 0, stream>>>(part, bg[l], bb[l], scale, shift,
                                                          Co[l], S, 1.0f / (B * Ho[l] * Ho[l]));
        cur = outb;
    }

    // conv5 output is in bufA; bufB (conv4 out) is dead -> reuse for partials
    bn_apply_t<<<(802816 + 255) / 256, 256, 0, stream>>>(cur, scale, shift, x5);
    {
        dim3 grid(FC1_KS, 16);
        fc1_gemm<<<grid, 256, 0, stream>>>(x5, l1w, bufB);
    }
    fc1_reduce<<<(32000 + 255) / 256, 256, 0, stream>>>(bufB, l1b, z1);
    fc2_v2<<<240, 256, 0, stream>>>(z1, l2w, l2b, ysb);
    spline_coeff<<<1, 96, 0, stream>>>(ysb, matrix, ca, cbuf, cc, cd);

    float* out = (float*)d_out;
    eval_img<<<(6291456 + 255) / 256, 256, 0, stream>>>(batch, ca, cbuf, cc, cd, out,
                                                        6291456, 65536);
    eval_tab<<<(96 * 255 + 255) / 256, 256, 0, stream>>>(ca, cbuf, cc, cd, out + 6291456,
                                                         96 * 255);
}

// Round 4
// 610.401 us; speedup vs baseline: 5.0986x; 1.8440x over previous
//
#include <hip/hip_runtime.h>
#include <hip/hip_bf16.h>

#define BEPS 1e-5f
#define FC1_KS 98
#define FC1_KC 256

typedef __attribute__((ext_vector_type(8))) short short8v;
typedef __attribute__((ext_vector_type(4))) float f32x4;
typedef unsigned short ushort_t;

// ---------------- conv1: fp32 implicit GEMM (K=27), bf16 out ----------------
__global__ __launch_bounds__(256) void conv_gemm(
    const float* __restrict__ in, const float* __restrict__ w,
    const float* __restrict__ effb, __hip_bfloat16* __restrict__ out,
    int B, int Ci, int Hi, int Wi, int Co, int Ho, int Wo) {
    const int HoWo = Ho * Wo;
    const int N = B * HoWo;
    const int K = Ci * 9;
    const int HiWi = Hi * Wi;
    __shared__ __align__(16) float As[16][64];
    __shared__ __align__(16) float Bs[16][64];
    const int tid = threadIdx.x;
    const int m0 = blockIdx.y * 64;
    const int n0 = blockIdx.x * 64;
    const int tm = tid >> 4;
    const int tn = tid & 15;

    int nb[4], npp[4];
    long long base[4];
    bool nv[4];
#pragma unroll
    for (int e = 0; e < 4; ++e) {
        int n = n0 + tn * 4 + e;
        nv[e] = (n < N);
        int nn = nv[e] ? n : 0;
        int b = nn / HoWo, p = nn - b * HoWo;
        int i = p / Wo, j = p - i * Wo;
        nb[e] = b; npp[e] = p;
        base[e] = (long long)b * Ci * HiWi + (2 * i) * Wi + 2 * j;
    }
    const int cA = tid >> 2;
    const int kqA = tid & 3;
    const int kkB = tid >> 4;

    float acc[4][4] = {};
    for (int k0 = 0; k0 < K; k0 += 16) {
#pragma unroll
        for (int e = 0; e < 4; ++e) {
            int k = k0 + kqA * 4 + e;
            int m = m0 + cA;
            As[kqA * 4 + e][cA] = (m < Co && k < K) ? w[(long long)m * K + k] : 0.f;
        }
        {
            int k = k0 + kkB;
            float v[4] = {0.f, 0.f, 0.f, 0.f};
            if (k < K) {
                int ci = k / 9, r = k - ci * 9;
                int dy = r / 3, dx = r - dy * 3;
                long long off = (long long)ci * HiWi + dy * Wi + dx;
#pragma unroll
                for (int e = 0; e < 4; ++e)
                    if (nv[e]) v[e] = in[base[e] + off];
            }
#pragma unroll
            for (int e = 0; e < 4; ++e) Bs[kkB][tn * 4 + e] = v[e];
        }
        __syncthreads();
#pragma unroll
        for (int kk = 0; kk < 16; ++kk) {
            float4 av = *(const float4*)&As[kk][tm * 4];
            float4 bv = *(const float4*)&Bs[kk][tn * 4];
            float a4[4] = {av.x, av.y, av.z, av.w};
            float b4[4] = {bv.x, bv.y, bv.z, bv.w};
#pragma unroll
            for (int mi = 0; mi < 4; ++mi)
#pragma unroll
                for (int ni = 0; ni < 4; ++ni)
                    acc[mi][ni] = fmaf(a4[mi], b4[ni], acc[mi][ni]);
        }
        __syncthreads();
    }
#pragma unroll
    for (int mi = 0; mi < 4; ++mi) {
        int m = m0 + tm * 4 + mi;
        if (m >= Co) continue;
        float bias = effb[m];
#pragma unroll
        for (int e = 0; e < 4; ++e) {
            if (!nv[e]) continue;
            out[((long long)nb[e] * Co + m) * HoWo + npp[e]] =
                __float2bfloat16(fmaxf(acc[mi][e] + bias, 0.f));
        }
    }
}

// ---------------- convs 2-5: bf16 MFMA implicit GEMM ------------------------
// tiles 64(M=Co) x 64(N=pix) x 32(K), 4 waves 2x2, each wave 32x32 via 2x2 frags
__global__ __launch_bounds__(256) void conv_mfma(
    const __hip_bfloat16* __restrict__ in, const ushort_t* __restrict__ wf,
    const float* __restrict__ effb, __hip_bfloat16* __restrict__ out,
    int B, int Ci, int Hi, int Wi, int Co, int Ho, int Wo, int K) {
    const int HoWo = Ho * Wo;
    const int N = B * HoWo;
    const int HiWi = Hi * Wi;
    __shared__ __align__(16) ushort_t As[64 * 40];  // [m][k] pad->40
    __shared__ __align__(16) ushort_t Bs[64 * 40];  // [n][k] pad->40
    const int tid = threadIdx.x;
    const int m0 = blockIdx.y * 64;
    const int n0 = blockIdx.x * 64;

    // staging ids: 64 rows x 4 threads, each thread 8 contiguous k
    const int srow = tid >> 2;
    const int skq = (tid & 3) * 8;
    // B pixel decode (one pixel per staging row)
    const int n = n0 + srow;
    const bool nv = (n < N);
    const int nn = nv ? n : 0;
    const int pb = nn / HoWo, pp = nn - pb * HoWo;
    const int pi = pp / Wo, pj = pp - pi * Wo;
    const long long binbase = (long long)pb * Ci * HiWi + (2 * pi) * Wi + 2 * pj;
    const ushort_t* inq = (const ushort_t*)in;
    const ushort_t* wrow = wf + (long long)(m0 + srow) * K + skq;

    // wave / fragment ids
    const int wid = tid >> 6;
    const int lane = tid & 63;
    const int wr = wid >> 1, wc = wid & 1;
    const int lm = lane & 15, lk = lane >> 4;

    f32x4 acc[2][2] = {};
    for (int k0 = 0; k0 < K; k0 += 32) {
        // stage A (weights): one 16B vector per thread
        *(short8v*)&As[srow * 40 + skq] = *(const short8v*)(wrow + k0);
        // stage B (im2col gather): 8 scalars -> one 16B LDS write
        short8v bvv;
#pragma unroll
        for (int j = 0; j < 8; ++j) {
            int k = k0 + skq + j;
            int ci = k / 9, rr = k - ci * 9;
            int dy = rr / 3, dx = rr - dy * 3;
            ushort_t v = nv ? inq[binbase + (long long)ci * HiWi + dy * Wi + dx] : (ushort_t)0;
            bvv[j] = (short)v;
        }
        *(short8v*)&Bs[srow * 40 + skq] = bvv;
        __syncthreads();
        short8v a0 = *(const short8v*)&As[(wr * 32 + lm) * 40 + lk * 8];
        short8v a1 = *(const short8v*)&As[(wr * 32 + 16 + lm) * 40 + lk * 8];
        short8v b0 = *(const short8v*)&Bs[(wc * 32 + lm) * 40 + lk * 8];
        short8v b1 = *(const short8v*)&Bs[(wc * 32 + 16 + lm) * 40 + lk * 8];
        acc[0][0] = __builtin_amdgcn_mfma_f32_16x16x32_bf16(a0, b0, acc[0][0], 0, 0, 0);
        acc[0][1] = __builtin_amdgcn_mfma_f32_16x16x32_bf16(a0, b1, acc[0][1], 0, 0, 0);
        acc[1][0] = __builtin_amdgcn_mfma_f32_16x16x32_bf16(a1, b0, acc[1][0], 0, 0, 0);
        acc[1][1] = __builtin_amdgcn_mfma_f32_16x16x32_bf16(a1, b1, acc[1][1], 0, 0, 0);
        __syncthreads();
    }
    // epilogue: D col(lane&15)=pixel, row((lane>>4)*4+reg)=co
#pragma unroll
    for (int nc = 0; nc < 2; ++nc) {
        int np = n0 + wc * 32 + nc * 16 + lm;
        if (np >= N) continue;
        int ob = np / HoWo, op = np - ob * HoWo;
#pragma unroll
        for (int mr = 0; mr < 2; ++mr) {
            int cobase = m0 + wr * 32 + mr * 16 + lk * 4;
#pragma unroll
            for (int r = 0; r < 4; ++r) {
                int co = cobase + r;
                float v = fmaxf(acc[mr][nc][r] + effb[co], 0.f);
                out[((long long)ob * Co + co) * HoWo + op] = __float2bfloat16(v);
            }
        }
    }
}

// ---------------- BN stats (bf16 input) -------------------------------------
__global__ void stats_partial(const __hip_bfloat16* __restrict__ y, float* __restrict__ part,
                              int B, int C, int HW, int S) {
    int c = blockIdx.x;
    int s = blockIdx.y;
    int tid = threadIdx.x;
    float sum = 0.f, sq = 0.f;
    for (int b = 0; b < B; ++b) {
        const __hip_bfloat16* yp = y + ((long long)b * C + c) * HW;
        for (int p = s * blockDim.x + tid; p < HW; p += S * blockDim.x) {
            float v = __bfloat162float(yp[p]);
            sum += v;
            sq = fmaf(v, v, sq);
        }
    }
    __shared__ float ls[256], lq[256];
    ls[tid] = sum; lq[tid] = sq;
    __syncthreads();
    for (int o = 128; o > 0; o >>= 1) {
        if (tid < o) { ls[tid] += ls[tid + o]; lq[tid] += lq[tid + o]; }
        __syncthreads();
    }
    if (tid == 0) {
        part[(c * S + s) * 2 + 0] = ls[0];
        part[(c * S + s) * 2 + 1] = lq[0];
    }
}

__global__ void stats_final(const float* __restrict__ part, const float* __restrict__ g,
                            const float* __restrict__ be, float* __restrict__ scale,
                            float* __restrict__ shift, int C, int S, float invN) {
    int c = blockIdx.x * blockDim.x + threadIdx.x;
    if (c >= C) return;
    float s = 0.f, q = 0.f;
    for (int i = 0; i < S; ++i) {
        s += part[(c * S + i) * 2 + 0];
        q += part[(c * S + i) * 2 + 1];
    }
    float m = s * invN;
    float v = q * invN - m * m;
    float inv = rsqrtf(v + BEPS);
    float sc = g[c] * inv;
    scale[c] = sc;
    shift[c] = be[c] - m * sc;
}

// ---------------- BN fold into next conv (bf16 weights out) ------------------
__global__ void fold_w_bf(const float* __restrict__ w, const float* __restrict__ scale,
                          ushort_t* __restrict__ wout, int Ci, int total) {
    int idx = blockIdx.x * blockDim.x + threadIdx.x;
    if (idx >= total) return;
    int ci = (idx / 9) % Ci;
    __hip_bfloat16 h = __float2bfloat16(w[idx] * scale[ci]);
    wout[idx] = *(ushort_t*)&h;
}

__global__ void fold_b(const float* __restrict__ w, const float* __restrict__ shift,
                       const float* __restrict__ bias, float* __restrict__ effb,
                       int Co, int Ci) {
    int co = blockIdx.x * blockDim.x + threadIdx.x;
    if (co >= Co) return;
    float acc = bias[co];
    const float* wr = w + (long long)co * Ci * 9;
    for (int ci = 0; ci < Ci; ++ci) {
        float sh = shift[ci];
#pragma unroll
        for (int t = 0; t < 9; ++t) acc = fmaf(wr[ci * 9 + t], sh, acc);
    }
    effb[co] = acc;
}

// ---------------- BN apply conv5 out (bf16) -> xT fp32 [k][32] --------------
__global__ void bn_apply_t(const __hip_bfloat16* __restrict__ y, const float* __restrict__ scale,
                           const float* __restrict__ shift, float* __restrict__ xT) {
    int idx = blockIdx.x * blockDim.x + threadIdx.x;
    if (idx >= 802816) return;
    int k = idx >> 5, b = idx & 31;
    int c = k / 49;
    xT[idx] = fmaf(__bfloat162float(y[(long long)b * 25088 + k]), scale[c], shift[c]);
}

// ---------------- fc1 split-K GEMM ------------------------------------------
__global__ __launch_bounds__(256) void fc1_gemm(const float* __restrict__ xT,
                                                const float* __restrict__ w,
                                                float* __restrict__ part) {
    const int K = 25088;
    __shared__ __align__(16) float As[16][64];
    __shared__ __align__(16) float Bs[16][32];
    const int tid = threadIdx.x;
    const int m0 = blockIdx.y * 64;
    const int kbeg = blockIdx.x * FC1_KC;
    const int cA = tid >> 2;
    const int kqA = (tid & 3) * 4;
    const int kkB = tid >> 5;
    const int bB = tid & 31;
    const int tm = tid >> 4;
    const int tn = tid & 15;

    const int mrow = m0 + cA;
    const bool mvalid = (mrow < 1000);
    const float* wrow = w + (long long)mrow * K + kbeg + kqA;

    float acc[4][2] = {};
    for (int k0 = 0; k0 < FC1_KC; k0 += 16) {
        float4 av = mvalid ? *(const float4*)(wrow + k0)
                           : make_float4(0.f, 0.f, 0.f, 0.f);
        As[kqA + 0][cA] = av.x;
        As[kqA + 1][cA] = av.y;
        As[kqA + 2][cA] = av.z;
        As[kqA + 3][cA] = av.w;
#pragma unroll
        for (int e = 0; e < 2; ++e) {
            int kk = kkB + e * 8;
            Bs[kk][bB] = xT[(kbeg + k0 + kk) * 32 + bB];
        }
        __syncthreads();
#pragma unroll
        for (int kk = 0; kk < 16; ++kk) {
            float4 a = *(const float4*)&As[kk][tm * 4];
            float b0 = Bs[kk][tn * 2 + 0];
            float b1 = Bs[kk][tn * 2 + 1];
            float a4[4] = {a.x, a.y, a.z, a.w};
#pragma unroll
            for (int mi = 0; mi < 4; ++mi) {
                acc[mi][0] = fmaf(a4[mi], b0, acc[mi][0]);
                acc[mi][1] = fmaf(a4[mi], b1, acc[mi][1]);
            }
        }
        __syncthreads();
    }
    float* pb = part + ((long long)blockIdx.y * FC1_KS + blockIdx.x) * 2048;
#pragma unroll
    for (int mi = 0; mi < 4; ++mi) {
        pb[(tm * 4 + mi) * 32 + tn * 2 + 0] = acc[mi][0];
        pb[(tm * 4 + mi) * 32 + tn * 2 + 1] = acc[mi][1];
    }
}

__global__ void fc1_reduce(const float* __restrict__ part, const float* __restrict__ bias,
                           float* __restrict__ z) {
    int idx = blockIdx.x * blockDim.x + threadIdx.x;
    if (idx >= 32000) return;
    int o = idx >> 5, b = idx & 31;
    int mt = o >> 6, mr = o & 63;
    const float* p = part + ((long long)mt * FC1_KS) * 2048 + mr * 32 + b;
    float s0 = 0.f, s1 = 0.f;
    int ks = 0;
    for (; ks + 1 < FC1_KS; ks += 2) {
        s0 += p[(long long)ks * 2048];
        s1 += p[(long long)(ks + 1) * 2048];
    }
    for (; ks < FC1_KS; ++ks) s0 += p[(long long)ks * 2048];
    z[b * 1000 + o] = fmaxf(s0 + s1 + bias[o], 0.f);
}

// ---------------- fc2 -------------------------------------------------------
__global__ __launch_bounds__(256) void fc2_v2(const float* __restrict__ z,
                                              const float* __restrict__ w,
                                              const float* __restrict__ bias,
                                              float* __restrict__ ys) {
    int gid = blockIdx.x * 4 + (threadIdx.x >> 6);
    int lane = threadIdx.x & 63;
    if (gid >= 960) return;
    int b = gid / 30, o = gid - b * 30;
    const float* zr = z + (long long)b * 1000;
    const float* wr = w + (long long)o * 1000;
    float acc = 0.f;
    for (int k = lane; k < 1000; k += 64) acc = fmaf(zr[k], wr[k], acc);
    for (int off = 32; off > 0; off >>= 1) acc += __shfl_down(acc, off, 64);
    if (lane == 0) ys[gid] = acc + bias[o];
}

// ---------------- spline coefficients ---------------------------------------
__global__ void spline_coeff(const float* __restrict__ ysraw, const float* __restrict__ matrix,
                             float* __restrict__ Ac, float* __restrict__ Bc,
                             float* __restrict__ Cc, float* __restrict__ Dc) {
    int r = threadIdx.x;
    if (r >= 96) return;
    const float h = 1.0f / 9.0f;
    float ya[10];
    int b = r / 3, ch = r % 3;
#pragma unroll
    for (int j = 0; j < 10; ++j)
        ya[j] = ysraw[b * 30 + ch * 10 + j] / 100.0f + (float)j / 9.0f;
    float M[10];
#pragma unroll
    for (int i = 0; i < 10; ++i) {
        float acc = 0.f;
#pragma unroll
        for (int j = 0; j < 10; ++j) acc = fmaf(matrix[i * 10 + j], ya[j], acc);
        M[i] = acc;
    }
#pragma unroll
    for (int k = 0; k < 9; ++k) {
        Ac[r * 9 + k] = (M[k + 1] - M[k]) / (6.0f * h);
        Bc[r * 9 + k] = M[k] * 0.5f;
        Cc[r * 9 + k] = (ya[k + 1] - ya[k]) / h - (M[k + 1] + 2.0f * M[k]) * (h / 6.0f);
        Dc[r * 9 + k] = ya[k];
    }
}

// ---------------- spline eval on the image ----------------------------------
__global__ void eval_img(const float* __restrict__ batch, const float* __restrict__ Ac,
                         const float* __restrict__ Bc, const float* __restrict__ Cc,
                         const float* __restrict__ Dc, float* __restrict__ out,
                         int total, int HW) {
    int idx = blockIdx.x * blockDim.x + threadIdx.x;
    if (idx >= total) return;
    int plane = idx / HW;
    float xv = batch[idx];
    const float h = 1.0f / 9.0f;
    int xi = (int)floorf(xv / h);
    xi = min(max(xi, 0), 8);
    float xf = xv - (float)xi * h;
    int ci = plane * 9 + xi;
    float a = Ac[ci], bb = Bc[ci], cc = Cc[ci], dd = Dc[ci];
    out[idx] = fmaf(fmaf(fmaf(a, xf, bb), xf, cc), xf, dd);
}

__global__ void eval_tab(const float* __restrict__ Ac, const float* __restrict__ Bc,
                         const float* __restrict__ Cc, const float* __restrict__ Dc,
                         float* __restrict__ out, int total) {
    int idx = blockIdx.x * blockDim.x + threadIdx.x;
    if (idx >= total) return;
    int plane = idx / 255;
    int j = idx % 255;
    float xv = (float)j / 255.0f;
    const float h = 1.0f / 9.0f;
    int xi = (int)floorf(xv / h);
    xi = min(max(xi, 0), 8);
    float xf = xv - (float)xi * h;
    int ci = plane * 9 + xi;
    float a = Ac[ci], bb = Bc[ci], cc = Cc[ci], dd = Dc[ci];
    out[idx] = fmaf(fmaf(fmaf(a, xf, bb), xf, cc), xf, dd);
}

extern "C" void kernel_launch(void* const* d_in, const int* in_sizes, int n_in,
                              void* d_out, int out_size, void* d_ws, size_t ws_size,
                              hipStream_t stream) {
    const int B = 32;
    const float* batch = (const float*)d_in[0];
    const float* cw[5] = {(const float*)d_in[1], (const float*)d_in[5], (const float*)d_in[9],
                          (const float*)d_in[13], (const float*)d_in[17]};
    const float* cb[5] = {(const float*)d_in[2], (const float*)d_in[6], (const float*)d_in[10],
                          (const float*)d_in[14], (const float*)d_in[18]};
    const float* bg[5] = {(const float*)d_in[3], (const float*)d_in[7], (const float*)d_in[11],
                          (const float*)d_in[15], (const float*)d_in[19]};
    const float* bb[5] = {(const float*)d_in[4], (const float*)d_in[8], (const float*)d_in[12],
                          (const float*)d_in[16], (const float*)d_in[20]};
    const float* l1w = (const float*)d_in[21];
    const float* l1b = (const float*)d_in[22];
    const float* l2w = (const float*)d_in[23];
    const float* l2b = (const float*)d_in[24];
    const float* matrix = (const float*)d_in[25];

    float* f = (float*)d_ws;
    const size_t A_F = 8258048;   // bufA: 16,516,096 bf16
    const size_t Bq_F = 4064256;  // bufB: 8,128,512 bf16
    const size_t W_F = 589824;    // Wf:   1,179,648 bf16
    __hip_bfloat16* bufA_bf = (__hip_bfloat16*)f;
    __hip_bfloat16* bufB_bf = (__hip_bfloat16*)(f + A_F);
    ushort_t* Wf_bf = (ushort_t*)(f + A_F + Bq_F);
    float* effb  = f + A_F + Bq_F + W_F;   // 512
    float* scale = effb + 512;             // 512
    float* shift = scale + 512;            // 512
    float* part  = shift + 512;            // 8192
    float* x5    = part + 8192;            // 802,816
    float* fc1p  = x5 + 802816;            // 3,211,264
    float* z1    = fc1p + 3211264;         // 32,000
    float* ysb   = z1 + 32000;             // 960
    float* ca    = ysb + 960;              // 864
    float* cbuf  = ca + 864;
    float* cc    = cbuf + 864;
    float* cd    = cc + 864;

    const int Ci[5] = {3, 32, 64, 128, 256};
    const int Co[5] = {32, 64, 128, 256, 512};
    const int Hi[5] = {256, 127, 63, 31, 15};
    const int Ho[5] = {127, 63, 31, 15, 7};
    const int S = 8;

    __hip_bfloat16* bufs[2] = {bufA_bf, bufB_bf};

    // layer 1: fp32 conv, bf16 out
    {
        int N = B * Ho[0] * Ho[0];
        dim3 grid((N + 63) / 64, (Co[0] + 63) / 64);
        conv_gemm<<<grid, 256, 0, stream>>>(batch, cw[0], cb[0], bufA_bf, B, Ci[0],
                                            Hi[0], Hi[0], Co[0], Ho[0], Ho[0]);
        stats_partial<<<dim3(Co[0], S), 256, 0, stream>>>(bufA_bf, part, B, Co[0],
                                                          Ho[0] * Ho[0], S);
        stats_final<<<1, 64, 0, stream>>>(part, bg[0], bb[0], scale, shift, Co[0], S,
                                          1.0f / (B * Ho[0] * Ho[0]));
    }

    // layers 2..5: MFMA bf16
    const __hip_bfloat16* cur = bufA_bf;
    for (int l = 1; l < 5; ++l) {
        __hip_bfloat16* outb = bufs[l % 2];
        int K = Ci[l] * 9;
        int wtotal = Co[l] * K;
        fold_w_bf<<<(wtotal + 255) / 256, 256, 0, stream>>>(cw[l], scale, Wf_bf, Ci[l], wtotal);
        fold_b<<<(Co[l] + 63) / 64, 64, 0, stream>>>(cw[l], shift, cb[l], effb, Co[l], Ci[l]);
        int N = B * Ho[l] * Ho[l];
        dim3 grid((N + 63) / 64, Co[l] / 64);
        conv_mfma<<<grid, 256, 0, stream>>>(cur, Wf_bf, effb, outb, B, Ci[l],
                                            Hi[l], Hi[l], Co[l], Ho[l], Ho[l], K);
        stats_partial<<<dim3(Co[l], S), 256, 0, stream>>>(outb, part, B, Co[l],
                                                          Ho[l] * Ho[l], S);
        stats_final<<<(Co[l] + 63) / 64, 64, 0, stream>>>(part, bg[l], bb[l], scale, shift,
                                                          Co[l], S, 1.0f / (B * Ho[l] * Ho[l]));
        cur = outb;
    }

    bn_apply_t<<<(802816 + 255) / 256, 256, 0, stream>>>(cur, scale, shift, x5);
    {
        dim3 grid(FC1_KS, 16);
        fc1_gemm<<<grid, 256, 0, stream>>>(x5, l1w, fc1p);
    }
    fc1_reduce<<<(32000 + 255) / 256, 256, 0, stream>>>(fc1p, l1b, z1);
    fc2_v2<<<240, 256, 0, stream>>>(z1, l2w, l2b, ysb);
    spline_coeff<<<1, 96, 0, stream>>>(ysb, matrix, ca, cbuf, cc, cd);

    float* out = (float*)d_out;
    eval_img<<<(6291456 + 255) / 256, 256, 0, stream>>>(batch, ca, cbuf, cc, cd, out,
                                                        6291456, 65536);
    eval_tab<<<(96 * 255 + 255) / 256, 256, 0, stream>>>(ca, cbuf, cc, cd, out + 6291456,
                                                         96 * 255);
}

// Round 5
// 529.504 us; speedup vs baseline: 5.8776x; 1.1528x over previous
//
#include <hip/hip_runtime.h>
#include <hip/hip_bf16.h>

#define BEPS 1e-5f
#define FC1_KS 98
#define FC1_KC 256

typedef __attribute__((ext_vector_type(8))) short short8v;
typedef __attribute__((ext_vector_type(4))) float f32x4;
typedef unsigned short ushort_t;

// ---------------- conv1: direct, fused BN-stats -----------------------------
// B=32,Ci=3,Hi=256,Co=32,Ho=127. One thread per output pixel, all 32 co.
__global__ __launch_bounds__(256) void conv1_direct(
    const float* __restrict__ in, const float* __restrict__ w,
    const float* __restrict__ bias, __hip_bfloat16* __restrict__ out,
    float* __restrict__ part2) {
    __shared__ float ws[864];
    __shared__ float bs[32];
    __shared__ float lsum[4][32], lsq[4][32];
    const int tid = threadIdx.x;
    for (int i = tid; i < 864; i += 256) ws[i] = w[i];
    if (tid < 32) bs[tid] = bias[tid];
    __syncthreads();

    const int TOT = 32 * 16129;
    int p = blockIdx.x * 256 + tid;
    const bool valid = (p < TOT);
    int pc = valid ? p : (TOT - 1);
    int b = pc / 16129, pp = pc - b * 16129;
    int i = pp / 127, j = pp - i * 127;
    const float* ib = in + ((long long)b * 3) * 65536 + (2 * i) * 256 + 2 * j;
    float patch[27];
#pragma unroll
    for (int ci = 0; ci < 3; ++ci)
#pragma unroll
        for (int di = 0; di < 3; ++di)
#pragma unroll
            for (int dj = 0; dj < 3; ++dj)
                patch[ci * 9 + di * 3 + dj] = ib[ci * 65536 + di * 256 + dj];

    const int lane = tid & 63, wid = tid >> 6;
    const float vm = valid ? 1.f : 0.f;
    for (int co = 0; co < 32; co += 4) {
        float a0 = bs[co], a1 = bs[co + 1], a2 = bs[co + 2], a3 = bs[co + 3];
#pragma unroll
        for (int t = 0; t < 27; ++t) {
            float pv = patch[t];
            a0 = fmaf(pv, ws[(co + 0) * 27 + t], a0);
            a1 = fmaf(pv, ws[(co + 1) * 27 + t], a1);
            a2 = fmaf(pv, ws[(co + 2) * 27 + t], a2);
            a3 = fmaf(pv, ws[(co + 3) * 27 + t], a3);
        }
        float r[4] = {fmaxf(a0, 0.f), fmaxf(a1, 0.f), fmaxf(a2, 0.f), fmaxf(a3, 0.f)};
#pragma unroll
        for (int u = 0; u < 4; ++u) {
            if (valid)
                out[((long long)b * 32 + co + u) * 16129 + pp] = __float2bfloat16(r[u]);
            float s = r[u] * vm, q = r[u] * r[u] * vm;
#pragma unroll
            for (int m = 1; m < 64; m <<= 1) {
                s += __shfl_xor(s, m, 64);
                q += __shfl_xor(q, m, 64);
            }
            if (lane == 0) { lsum[wid][co + u] = s; lsq[wid][co + u] = q; }
        }
    }
    __syncthreads();
    if (tid < 32) {
        part2[blockIdx.x * 64 + tid * 2 + 0] =
            lsum[0][tid] + lsum[1][tid] + lsum[2][tid] + lsum[3][tid];
        part2[blockIdx.x * 64 + tid * 2 + 1] =
            lsq[0][tid] + lsq[1][tid] + lsq[2][tid] + lsq[3][tid];
    }
}

// combine conv1 per-block stats -> scale/shift
__global__ void conv1_stats_final(const float* __restrict__ part2, const float* __restrict__ g,
                                  const float* __restrict__ be, float* __restrict__ scale,
                                  float* __restrict__ shift, int NB, float invN) {
    __shared__ float ss[256], sq_[256];
    int tid = threadIdx.x;
    int c = tid >> 3, sl = tid & 7;
    float s = 0.f, q = 0.f;
    for (int i = sl; i < NB; i += 8) {
        s += part2[i * 64 + c * 2 + 0];
        q += part2[i * 64 + c * 2 + 1];
    }
    ss[tid] = s; sq_[tid] = q;
    __syncthreads();
    if ((tid & 7) == 0) {
        float S = 0.f, Q = 0.f;
#pragma unroll
        for (int u = 0; u < 8; ++u) { S += ss[tid + u]; Q += sq_[tid + u]; }
        float m = S * invN;
        float v = Q * invN - m * m;
        float inv = rsqrtf(v + BEPS);
        float sc = g[c] * inv;
        scale[c] = sc;
        shift[c] = be[c] - m * sc;
    }
}

// ---------------- convs 2-5: bf16 MFMA implicit GEMM ------------------------
// tiles 64(M=Co) x 64(N=pix) x 32(K); koff LDS table; optional K-split partials
__global__ __launch_bounds__(256) void conv_mfma(
    const __hip_bfloat16* __restrict__ in, const ushort_t* __restrict__ wf,
    const float* __restrict__ effb, __hip_bfloat16* __restrict__ out,
    float* __restrict__ pacc,
    int B, int Ci, int Hi, int Wi, int Co, int Ho, int Wo, int K, int kcount) {
    const int HoWo = Ho * Wo;
    const int N = B * HoWo;
    const int HiWi = Hi * Wi;
    __shared__ __align__(16) ushort_t As[64 * 40];
    __shared__ __align__(16) ushort_t Bs[64 * 40];
    __shared__ int koff[1152];
    const int tid = threadIdx.x;
    const int m0 = blockIdx.y * 64;
    const int n0 = blockIdx.x * 64;
    const int kbeg = blockIdx.z * kcount;

    for (int k = tid; k < kcount; k += 256) {
        int kg = kbeg + k;
        int ci = kg / 9, r = kg - ci * 9;
        int dy = r / 3, dx = r - dy * 3;
        koff[k] = ci * HiWi + dy * Wi + dx;
    }

    const int srow = tid >> 2;
    const int skq = (tid & 3) * 8;
    const int n = n0 + srow;
    const bool nv = (n < N);
    const int nn = nv ? n : 0;
    const int pb = nn / HoWo, pp = nn - pb * HoWo;
    const int pi = pp / Wo, pj = pp - pi * Wo;
    const long long binbase = (long long)pb * Ci * HiWi + (2 * pi) * Wi + 2 * pj;
    const ushort_t* inq = (const ushort_t*)in;
    const ushort_t* wrow = wf + (long long)(m0 + srow) * K + kbeg + skq;

    const int wid = tid >> 6;
    const int lane = tid & 63;
    const int wr = wid >> 1, wc = wid & 1;
    const int lm = lane & 15, lk = lane >> 4;

    __syncthreads();  // koff ready

    f32x4 acc[2][2] = {};
    for (int k0 = 0; k0 < kcount; k0 += 32) {
        *(short8v*)&As[srow * 40 + skq] = *(const short8v*)(wrow + k0);
        short8v bvv;
#pragma unroll
        for (int j = 0; j < 8; ++j) {
            ushort_t v = nv ? inq[binbase + koff[k0 + skq + j]] : (ushort_t)0;
            bvv[j] = (short)v;
        }
        *(short8v*)&Bs[srow * 40 + skq] = bvv;
        __syncthreads();
        short8v a0 = *(const short8v*)&As[(wr * 32 + lm) * 40 + lk * 8];
        short8v a1 = *(const short8v*)&As[(wr * 32 + 16 + lm) * 40 + lk * 8];
        short8v b0 = *(const short8v*)&Bs[(wc * 32 + lm) * 40 + lk * 8];
        short8v b1 = *(const short8v*)&Bs[(wc * 32 + 16 + lm) * 40 + lk * 8];
        acc[0][0] = __builtin_amdgcn_mfma_f32_16x16x32_bf16(a0, b0, acc[0][0], 0, 0, 0);
        acc[0][1] = __builtin_amdgcn_mfma_f32_16x16x32_bf16(a0, b1, acc[0][1], 0, 0, 0);
        acc[1][0] = __builtin_amdgcn_mfma_f32_16x16x32_bf16(a1, b0, acc[1][0], 0, 0, 0);
        acc[1][1] = __builtin_amdgcn_mfma_f32_16x16x32_bf16(a1, b1, acc[1][1], 0, 0, 0);
        __syncthreads();
    }
    if (pacc) {
        float* pbuf = pacc + (long long)blockIdx.z * Co * N;
#pragma unroll
        for (int nc = 0; nc < 2; ++nc) {
            int np = n0 + wc * 32 + nc * 16 + lm;
            if (np >= N) continue;
#pragma unroll
            for (int mr = 0; mr < 2; ++mr) {
                int cobase = m0 + wr * 32 + mr * 16 + lk * 4;
#pragma unroll
                for (int r = 0; r < 4; ++r)
                    pbuf[(long long)(cobase + r) * N + np] = acc[mr][nc][r];
            }
        }
    } else {
#pragma unroll
        for (int nc = 0; nc < 2; ++nc) {
            int np = n0 + wc * 32 + nc * 16 + lm;
            if (np >= N) continue;
            int ob = np / HoWo, op = np - ob * HoWo;
#pragma unroll
            for (int mr = 0; mr < 2; ++mr) {
                int cobase = m0 + wr * 32 + mr * 16 + lk * 4;
#pragma unroll
                for (int r = 0; r < 4; ++r) {
                    int co = cobase + r;
                    float v = fmaxf(acc[mr][nc][r] + effb[co], 0.f);
                    out[((long long)ob * Co + co) * HoWo + op] = __float2bfloat16(v);
                }
            }
        }
    }
}

// reduce conv5 K-split partials + bias + relu -> bf16 NCHW
__global__ void conv5_reduce(const float* __restrict__ pacc, const float* __restrict__ effb,
                             __hip_bfloat16* __restrict__ out) {
    int idx = blockIdx.x * 256 + threadIdx.x;
    if (idx >= 512 * 1568) return;
    int co = idx / 1568, n = idx - co * 1568;
    const long long st = (long long)512 * 1568;
    float s = pacc[(long long)co * 1568 + n] + pacc[st + (long long)co * 1568 + n] +
              pacc[2 * st + (long long)co * 1568 + n] + effb[co];
    s = fmaxf(s, 0.f);
    int b = n / 49, p = n - b * 49;
    out[((long long)b * 512 + co) * 49 + p] = __float2bfloat16(s);
}

// ---------------- BN stats (bf16 input), layers 2..5 ------------------------
__global__ void stats_partial(const __hip_bfloat16* __restrict__ y, float* __restrict__ part,
                              int B, int C, int HW, int S) {
    int c = blockIdx.x;
    int s = blockIdx.y;
    int tid = threadIdx.x;
    float sum = 0.f, sq = 0.f;
    for (int b = 0; b < B; ++b) {
        const __hip_bfloat16* yp = y + ((long long)b * C + c) * HW;
        for (int p = s * blockDim.x + tid; p < HW; p += S * blockDim.x) {
            float v = __bfloat162float(yp[p]);
            sum += v;
            sq = fmaf(v, v, sq);
        }
    }
    __shared__ float ls[256], lq[256];
    ls[tid] = sum; lq[tid] = sq;
    __syncthreads();
    for (int o = 128; o > 0; o >>= 1) {
        if (tid < o) { ls[tid] += ls[tid + o]; lq[tid] += lq[tid + o]; }
        __syncthreads();
    }
    if (tid == 0) {
        part[(c * S + s) * 2 + 0] = ls[0];
        part[(c * S + s) * 2 + 1] = lq[0];
    }
}

__global__ void stats_final(const float* __restrict__ part, const float* __restrict__ g,
                            const float* __restrict__ be, float* __restrict__ scale,
                            float* __restrict__ shift, int C, int S, float invN) {
    int c = blockIdx.x * blockDim.x + threadIdx.x;
    if (c >= C) return;
    float s = 0.f, q = 0.f;
    for (int i = 0; i < S; ++i) {
        s += part[(c * S + i) * 2 + 0];
        q += part[(c * S + i) * 2 + 1];
    }
    float m = s * invN;
    float v = q * invN - m * m;
    float inv = rsqrtf(v + BEPS);
    float sc = g[c] * inv;
    scale[c] = sc;
    shift[c] = be[c] - m * sc;
}

// ---------------- BN fold into next conv ------------------------------------
__global__ void fold_w_bf(const float* __restrict__ w, const float* __restrict__ scale,
                          ushort_t* __restrict__ wout, int Ci, int total) {
    int idx = blockIdx.x * blockDim.x + threadIdx.x;
    if (idx >= total) return;
    int ci = (idx / 9) % Ci;
    __hip_bfloat16 h = __float2bfloat16(w[idx] * scale[ci]);
    wout[idx] = *(ushort_t*)&h;
}

__global__ void fold_b(const float* __restrict__ w, const float* __restrict__ shift,
                       const float* __restrict__ bias, float* __restrict__ effb,
                       int Co, int Ci) {
    int co = blockIdx.x * blockDim.x + threadIdx.x;
    if (co >= Co) return;
    float acc = bias[co];
    const float* wr = w + (long long)co * Ci * 9;
    for (int ci = 0; ci < Ci; ++ci) {
        float sh = shift[ci];
#pragma unroll
        for (int t = 0; t < 9; ++t) acc = fmaf(wr[ci * 9 + t], sh, acc);
    }
    effb[co] = acc;
}

// ---------------- BN apply conv5 out (bf16) -> xT fp32 [k][32] --------------
__global__ void bn_apply_t(const __hip_bfloat16* __restrict__ y, const float* __restrict__ scale,
                           const float* __restrict__ shift, float* __restrict__ xT) {
    int idx = blockIdx.x * blockDim.x + threadIdx.x;
    if (idx >= 802816) return;
    int k = idx >> 5, b = idx & 31;
    int c = k / 49;
    xT[idx] = fmaf(__bfloat162float(y[(long long)b * 25088 + k]), scale[c], shift[c]);
}

// ---------------- fc1 split-K GEMM ------------------------------------------
__global__ __launch_bounds__(256) void fc1_gemm(const float* __restrict__ xT,
                                                const float* __restrict__ w,
                                                float* __restrict__ part) {
    const int K = 25088;
    __shared__ __align__(16) float As[16][64];
    __shared__ __align__(16) float Bs[16][32];
    const int tid = threadIdx.x;
    const int m0 = blockIdx.y * 64;
    const int kbeg = blockIdx.x * FC1_KC;
    const int cA = tid >> 2;
    const int kqA = (tid & 3) * 4;
    const int kkB = tid >> 5;
    const int bB = tid & 31;
    const int tm = tid >> 4;
    const int tn = tid & 15;

    const int mrow = m0 + cA;
    const bool mvalid = (mrow < 1000);
    const float* wrow = w + (long long)mrow * K + kbeg + kqA;

    float acc[4][2] = {};
    for (int k0 = 0; k0 < FC1_KC; k0 += 16) {
        float4 av = mvalid ? *(const float4*)(wrow + k0)
                           : make_float4(0.f, 0.f, 0.f, 0.f);
        As[kqA + 0][cA] = av.x;
        As[kqA + 1][cA] = av.y;
        As[kqA + 2][cA] = av.z;
        As[kqA + 3][cA] = av.w;
#pragma unroll
        for (int e = 0; e < 2; ++e) {
            int kk = kkB + e * 8;
            Bs[kk][bB] = xT[(kbeg + k0 + kk) * 32 + bB];
        }
        __syncthreads();
#pragma unroll
        for (int kk = 0; kk < 16; ++kk) {
            float4 a = *(const float4*)&As[kk][tm * 4];
            float b0 = Bs[kk][tn * 2 + 0];
            float b1 = Bs[kk][tn * 2 + 1];
            float a4[4] = {a.x, a.y, a.z, a.w};
#pragma unroll
            for (int mi = 0; mi < 4; ++mi) {
                acc[mi][0] = fmaf(a4[mi], b0, acc[mi][0]);
                acc[mi][1] = fmaf(a4[mi], b1, acc[mi][1]);
            }
        }
        __syncthreads();
    }
    float* pb = part + ((long long)blockIdx.y * FC1_KS + blockIdx.x) * 2048;
#pragma unroll
    for (int mi = 0; mi < 4; ++mi) {
        pb[(tm * 4 + mi) * 32 + tn * 2 + 0] = acc[mi][0];
        pb[(tm * 4 + mi) * 32 + tn * 2 + 1] = acc[mi][1];
    }
}

__global__ void fc1_reduce(const float* __restrict__ part, const float* __restrict__ bias,
                           float* __restrict__ z) {
    int idx = blockIdx.x * blockDim.x + threadIdx.x;
    if (idx >= 32000) return;
    int o = idx >> 5, b = idx & 31;
    int mt = o >> 6, mr = o & 63;
    const float* p = part + ((long long)mt * FC1_KS) * 2048 + mr * 32 + b;
    float s0 = 0.f, s1 = 0.f;
    int ks = 0;
    for (; ks + 1 < FC1_KS; ks += 2) {
        s0 += p[(long long)ks * 2048];
        s1 += p[(long long)(ks + 1) * 2048];
    }
    for (; ks < FC1_KS; ++ks) s0 += p[(long long)ks * 2048];
    z[b * 1000 + o] = fmaxf(s0 + s1 + bias[o], 0.f);
}

// ---------------- fc2 -------------------------------------------------------
__global__ __launch_bounds__(256) void fc2_v2(const float* __restrict__ z,
                                              const float* __restrict__ w,
                                              const float* __restrict__ bias,
                                              float* __restrict__ ys) {
    int gid = blockIdx.x * 4 + (threadIdx.x >> 6);
    int lane = threadIdx.x & 63;
    if (gid >= 960) return;
    int b = gid / 30, o = gid - b * 30;
    const float* zr = z + (long long)b * 1000;
    const float* wr = w + (long long)o * 1000;
    float acc = 0.f;
    for (int k = lane; k < 1000; k += 64) acc = fmaf(zr[k], wr[k], acc);
    for (int off = 32; off > 0; off >>= 1) acc += __shfl_down(acc, off, 64);
    if (lane == 0) ys[gid] = acc + bias[o];
}

// ---------------- spline coefficients -> float4 per segment -----------------
__global__ void spline_coeff(const float* __restrict__ ysraw, const float* __restrict__ matrix,
                             float4* __restrict__ coef) {
    int r = threadIdx.x;
    if (r >= 96) return;
    const float h = 1.0f / 9.0f;
    float ya[10];
    int b = r / 3, ch = r % 3;
#pragma unroll
    for (int j = 0; j < 10; ++j)
        ya[j] = ysraw[b * 30 + ch * 10 + j] / 100.0f + (float)j / 9.0f;
    float M[10];
#pragma unroll
    for (int i = 0; i < 10; ++i) {
        float acc = 0.f;
#pragma unroll
        for (int j = 0; j < 10; ++j) acc = fmaf(matrix[i * 10 + j], ya[j], acc);
        M[i] = acc;
    }
#pragma unroll
    for (int k = 0; k < 9; ++k) {
        float a = (M[k + 1] - M[k]) / (6.0f * h);
        float bb = M[k] * 0.5f;
        float cc = (ya[k + 1] - ya[k]) / h - (M[k + 1] + 2.0f * M[k]) * (h / 6.0f);
        float dd = ya[k];
        coef[r * 9 + k] = make_float4(a, bb, cc, dd);
    }
}

// ---------------- spline eval on the image (float4) -------------------------
__global__ void eval_img4(const float4* __restrict__ batch4, const float4* __restrict__ coef,
                          float4* __restrict__ out4) {
    int idx = blockIdx.x * blockDim.x + threadIdx.x;
    if (idx >= 1572864) return;
    int plane = idx >> 14;  // 16384 float4 per plane (65536/4)
    float4 xv4 = batch4[idx];
    const float h = 1.0f / 9.0f;
    float xin[4] = {xv4.x, xv4.y, xv4.z, xv4.w};
    float xout[4];
#pragma unroll
    for (int e = 0; e < 4; ++e) {
        float xv = xin[e];
        int xi = (int)floorf(xv / h);
        xi = min(max(xi, 0), 8);
        float xf = xv - (float)xi * h;
        float4 cf = coef[plane * 9 + xi];
        xout[e] = fmaf(fmaf(fmaf(cf.x, xf, cf.y), xf, cf.z), xf, cf.w);
    }
    out4[idx] = make_float4(xout[0], xout[1], xout[2], xout[3]);
}

// ---------------- spline eval on the 255-value table ------------------------
__global__ void eval_tab(const float4* __restrict__ coef, float* __restrict__ out, int total) {
    int idx = blockIdx.x * blockDim.x + threadIdx.x;
    if (idx >= total) return;
    int plane = idx / 255;
    int j = idx % 255;
    float xv = (float)j / 255.0f;
    const float h = 1.0f / 9.0f;
    int xi = (int)floorf(xv / h);
    xi = min(max(xi, 0), 8);
    float xf = xv - (float)xi * h;
    float4 cf = coef[plane * 9 + xi];
    out[idx] = fmaf(fmaf(fmaf(cf.x, xf, cf.y), xf, cf.z), xf, cf.w);
}

extern "C" void kernel_launch(void* const* d_in, const int* in_sizes, int n_in,
                              void* d_out, int out_size, void* d_ws, size_t ws_size,
                              hipStream_t stream) {
    const int B = 32;
    const float* batch = (const float*)d_in[0];
    const float* cw[5] = {(const float*)d_in[1], (const float*)d_in[5], (const float*)d_in[9],
                          (const float*)d_in[13], (const float*)d_in[17]};
    const float* cb[5] = {(const float*)d_in[2], (const float*)d_in[6], (const float*)d_in[10],
                          (const float*)d_in[14], (const float*)d_in[18]};
    const float* bg[5] = {(const float*)d_in[3], (const float*)d_in[7], (const float*)d_in[11],
                          (const float*)d_in[15], (const float*)d_in[19]};
    const float* bb[5] = {(const float*)d_in[4], (const float*)d_in[8], (const float*)d_in[12],
                          (const float*)d_in[16], (const float*)d_in[20]};
    const float* l1w = (const float*)d_in[21];
    const float* l1b = (const float*)d_in[22];
    const float* l2w = (const float*)d_in[23];
    const float* l2b = (const float*)d_in[24];
    const float* matrix = (const float*)d_in[25];

    float* f = (float*)d_ws;
    const size_t A_F = 8258048;   // bufA bf16 storage
    const size_t Bq_F = 4064256;  // bufB bf16 storage
    const size_t W_F = 589824;    // folded weights bf16
    __hip_bfloat16* bufA_bf = (__hip_bfloat16*)f;
    __hip_bfloat16* bufB_bf = (__hip_bfloat16*)(f + A_F);
    ushort_t* Wf_bf = (ushort_t*)(f + A_F + Bq_F);
    float* effb  = f + A_F + Bq_F + W_F;   // 512
    float* scale = effb + 512;             // 512
    float* shift = scale + 512;            // 512
    float* part  = shift + 512;            // 8192
    float* part2 = part + 8192;            // 2017*64 = 129,088
    float* x5    = part2 + 129088;         // 802,816
    float* fc1p  = x5 + 802816;            // 3,211,264 (shared with conv5 pacc 2,408,448)
    float* z1    = fc1p + 3211264;         // 32,000
    float* ysb   = z1 + 32000;             // 960
    float4* coef = (float4*)(ysb + 960);   // 96*9 float4 = 3,456 floats

    const int Ci[5] = {3, 32, 64, 128, 256};
    const int Co[5] = {32, 64, 128, 256, 512};
    const int Hi[5] = {256, 127, 63, 31, 15};
    const int Ho[5] = {127, 63, 31, 15, 7};
    const int S = 8;

    __hip_bfloat16* bufs[2] = {bufA_bf, bufB_bf};

    // layer 1: direct conv + fused stats
    {
        int NB = (32 * 16129 + 255) / 256;  // 2017
        conv1_direct<<<NB, 256, 0, stream>>>(batch, cw[0], cb[0], bufA_bf, part2);
        conv1_stats_final<<<1, 256, 0, stream>>>(part2, bg[0], bb[0], scale, shift, NB,
                                                 1.0f / (32 * 16129));
    }

    // layers 2..5: MFMA bf16
    const __hip_bfloat16* cur = bufA_bf;
    for (int l = 1; l < 5; ++l) {
        __hip_bfloat16* outb = bufs[l % 2];
        int K = Ci[l] * 9;
        int wtotal = Co[l] * K;
        fold_w_bf<<<(wtotal + 255) / 256, 256, 0, stream>>>(cw[l], scale, Wf_bf, Ci[l], wtotal);
        fold_b<<<(Co[l] + 63) / 64, 64, 0, stream>>>(cw[l], shift, cb[l], effb, Co[l], Ci[l]);
        int N = B * Ho[l] * Ho[l];
        if (l < 4) {
            dim3 grid((N + 63) / 64, Co[l] / 64, 1);
            conv_mfma<<<grid, 256, 0, stream>>>(cur, Wf_bf, effb, outb, nullptr, B, Ci[l],
                                                Hi[l], Hi[l], Co[l], Ho[l], Ho[l], K, K);
        } else {
            dim3 grid((N + 63) / 64, Co[l] / 64, 3);  // K=2304 -> 3x768
            conv_mfma<<<grid, 256, 0, stream>>>(cur, Wf_bf, effb, nullptr, fc1p, B, Ci[l],
                                                Hi[l], Hi[l], Co[l], Ho[l], Ho[l], K, 768);
            conv5_reduce<<<(512 * 1568 + 255) / 256, 256, 0, stream>>>(fc1p, effb, outb);
        }
        stats_partial<<<dim3(Co[l], S), 256, 0, stream>>>(outb, part, B, Co[l],
                                                          Ho[l] * Ho[l], S);
        stats_final<<<(Co[l] + 63) / 64, 64, 0, stream>>>(part, bg[l], bb[l], scale, shift,
                                                          Co[l], S, 1.0f / (B * Ho[l] * Ho[l]));
        cur = outb;
    }

    bn_apply_t<<<(802816 + 255) / 256, 256, 0, stream>>>(cur, scale, shift, x5);
    {
        dim3 grid(FC1_KS, 16);
        fc1_gemm<<<grid, 256, 0, stream>>>(x5, l1w, fc1p);
    }
    fc1_reduce<<<(32000 + 255) / 256, 256, 0, stream>>>(fc1p, l1b, z1);
    fc2_v2<<<240, 256, 0, stream>>>(z1, l2w, l2b, ysb);
    spline_coeff<<<1, 96, 0, stream>>>(ysb, matrix, coef);

    float* out = (float*)d_out;
    eval_img4<<<(1572864 + 255) / 256, 256, 0, stream>>>((const float4*)batch, coef,
                                                         (float4*)out);
    eval_tab<<<(96 * 255 + 255) / 256, 256, 0, stream>>>(coef, out + 6291456, 96 * 255);
}

// Round 6
// 466.196 us; speedup vs baseline: 6.6757x; 1.1358x over previous
//
#include <hip/hip_runtime.h>
#include <hip/hip_bf16.h>

#define BEPS 1e-5f
#define FC1_KS 98
#define FC1_KC 256
#define C1NB 2017
#define C1ST 2048

typedef __attribute__((ext_vector_type(8))) short short8v;
typedef __attribute__((ext_vector_type(4))) float f32x4;
typedef unsigned short ushort_t;

// ---------------- conv1: direct, fused BN-stats -----------------------------
// B=32,Ci=3,Hi=256,Co=32,Ho=127. One thread per output pixel, all 32 co.
// partials written TRANSPOSED: part2T[(c*2+u)][block] for coalesced reduce.
__global__ __launch_bounds__(256) void conv1_direct(
    const float* __restrict__ in, const float* __restrict__ w,
    const float* __restrict__ bias, __hip_bfloat16* __restrict__ out,
    float* __restrict__ part2T) {
    __shared__ float ws[864];
    __shared__ float bs[32];
    __shared__ float lsum[4][32], lsq[4][32];
    const int tid = threadIdx.x;
    for (int i = tid; i < 864; i += 256) ws[i] = w[i];
    if (tid < 32) bs[tid] = bias[tid];
    __syncthreads();

    const int TOT = 32 * 16129;
    int p = blockIdx.x * 256 + tid;
    const bool valid = (p < TOT);
    int pc = valid ? p : (TOT - 1);
    int b = pc / 16129, pp = pc - b * 16129;
    int i = pp / 127, j = pp - i * 127;
    const float* ib = in + ((long long)b * 3) * 65536 + (2 * i) * 256 + 2 * j;
    float patch[27];
#pragma unroll
    for (int ci = 0; ci < 3; ++ci)
#pragma unroll
        for (int di = 0; di < 3; ++di)
#pragma unroll
            for (int dj = 0; dj < 3; ++dj)
                patch[ci * 9 + di * 3 + dj] = ib[ci * 65536 + di * 256 + dj];

    const int lane = tid & 63, wid = tid >> 6;
    const float vm = valid ? 1.f : 0.f;
    for (int co = 0; co < 32; co += 4) {
        float a0 = bs[co], a1 = bs[co + 1], a2 = bs[co + 2], a3 = bs[co + 3];
#pragma unroll
        for (int t = 0; t < 27; ++t) {
            float pv = patch[t];
            a0 = fmaf(pv, ws[(co + 0) * 27 + t], a0);
            a1 = fmaf(pv, ws[(co + 1) * 27 + t], a1);
            a2 = fmaf(pv, ws[(co + 2) * 27 + t], a2);
            a3 = fmaf(pv, ws[(co + 3) * 27 + t], a3);
        }
        float r[4] = {fmaxf(a0, 0.f), fmaxf(a1, 0.f), fmaxf(a2, 0.f), fmaxf(a3, 0.f)};
#pragma unroll
        for (int u = 0; u < 4; ++u) {
            if (valid)
                out[((long long)b * 32 + co + u) * 16129 + pp] = __float2bfloat16(r[u]);
            float s = r[u] * vm, q = r[u] * r[u] * vm;
#pragma unroll
            for (int m = 1; m < 64; m <<= 1) {
                s += __shfl_xor(s, m, 64);
                q += __shfl_xor(q, m, 64);
            }
            if (lane == 0) { lsum[wid][co + u] = s; lsq[wid][co + u] = q; }
        }
    }
    __syncthreads();
    if (tid < 32) {
        part2T[(tid * 2 + 0) * C1ST + blockIdx.x] =
            lsum[0][tid] + lsum[1][tid] + lsum[2][tid] + lsum[3][tid];
        part2T[(tid * 2 + 1) * C1ST + blockIdx.x] =
            lsq[0][tid] + lsq[1][tid] + lsq[2][tid] + lsq[3][tid];
    }
}

// combine conv1 per-block stats -> scale/shift. 32 blocks (one per channel).
__global__ __launch_bounds__(256) void conv1_stats_final(
    const float* __restrict__ part2T, const float* __restrict__ g,
    const float* __restrict__ be, float* __restrict__ scale,
    float* __restrict__ shift, int NB, float invN) {
    const int c = blockIdx.x;
    const int tid = threadIdx.x;
    float s = 0.f, q = 0.f;
    const float* rs = part2T + (c * 2 + 0) * C1ST;
    const float* rq = part2T + (c * 2 + 1) * C1ST;
    for (int i = tid; i < NB; i += 256) {
        s += rs[i];
        q += rq[i];
    }
#pragma unroll
    for (int m = 1; m < 64; m <<= 1) {
        s += __shfl_xor(s, m, 64);
        q += __shfl_xor(q, m, 64);
    }
    __shared__ float ls[4], lq[4];
    int wid = tid >> 6, lane = tid & 63;
    if (lane == 0) { ls[wid] = s; lq[wid] = q; }
    __syncthreads();
    if (tid == 0) {
        float S = ls[0] + ls[1] + ls[2] + ls[3];
        float Q = lq[0] + lq[1] + lq[2] + lq[3];
        float m = S * invN;
        float v = Q * invN - m * m;
        float inv = rsqrtf(v + BEPS);
        float sc = g[c] * inv;
        scale[c] = sc;
        shift[c] = be[c] - m * sc;
    }
}

// ---------------- convs 2-5: bf16 MFMA implicit GEMM ------------------------
__global__ __launch_bounds__(256) void conv_mfma(
    const __hip_bfloat16* __restrict__ in, const ushort_t* __restrict__ wf,
    const float* __restrict__ effb, __hip_bfloat16* __restrict__ out,
    float* __restrict__ pacc,
    int B, int Ci, int Hi, int Wi, int Co, int Ho, int Wo, int K, int kcount) {
    const int HoWo = Ho * Wo;
    const int N = B * HoWo;
    const int HiWi = Hi * Wi;
    __shared__ __align__(16) ushort_t As[64 * 40];
    __shared__ __align__(16) ushort_t Bs[64 * 40];
    __shared__ int koff[1152];
    const int tid = threadIdx.x;
    const int m0 = blockIdx.y * 64;
    const int n0 = blockIdx.x * 64;
    const int kbeg = blockIdx.z * kcount;

    for (int k = tid; k < kcount; k += 256) {
        int kg = kbeg + k;
        int ci = kg / 9, r = kg - ci * 9;
        int dy = r / 3, dx = r - dy * 3;
        koff[k] = ci * HiWi + dy * Wi + dx;
    }

    const int srow = tid >> 2;
    const int skq = (tid & 3) * 8;
    const int n = n0 + srow;
    const bool nv = (n < N);
    const int nn = nv ? n : 0;
    const int pb = nn / HoWo, pp = nn - pb * HoWo;
    const int pi = pp / Wo, pj = pp - pi * Wo;
    const long long binbase = (long long)pb * Ci * HiWi + (2 * pi) * Wi + 2 * pj;
    const ushort_t* inq = (const ushort_t*)in;
    const ushort_t* wrow = wf + (long long)(m0 + srow) * K + kbeg + skq;

    const int wid = tid >> 6;
    const int lane = tid & 63;
    const int wr = wid >> 1, wc = wid & 1;
    const int lm = lane & 15, lk = lane >> 4;

    __syncthreads();  // koff ready

    f32x4 acc[2][2] = {};
    for (int k0 = 0; k0 < kcount; k0 += 32) {
        *(short8v*)&As[srow * 40 + skq] = *(const short8v*)(wrow + k0);
        short8v bvv;
#pragma unroll
        for (int j = 0; j < 8; ++j) {
            ushort_t v = nv ? inq[binbase + koff[k0 + skq + j]] : (ushort_t)0;
            bvv[j] = (short)v;
        }
        *(short8v*)&Bs[srow * 40 + skq] = bvv;
        __syncthreads();
        short8v a0 = *(const short8v*)&As[(wr * 32 + lm) * 40 + lk * 8];
        short8v a1 = *(const short8v*)&As[(wr * 32 + 16 + lm) * 40 + lk * 8];
        short8v b0 = *(const short8v*)&Bs[(wc * 32 + lm) * 40 + lk * 8];
        short8v b1 = *(const short8v*)&Bs[(wc * 32 + 16 + lm) * 40 + lk * 8];
        acc[0][0] = __builtin_amdgcn_mfma_f32_16x16x32_bf16(a0, b0, acc[0][0], 0, 0, 0);
        acc[0][1] = __builtin_amdgcn_mfma_f32_16x16x32_bf16(a0, b1, acc[0][1], 0, 0, 0);
        acc[1][0] = __builtin_amdgcn_mfma_f32_16x16x32_bf16(a1, b0, acc[1][0], 0, 0, 0);
        acc[1][1] = __builtin_amdgcn_mfma_f32_16x16x32_bf16(a1, b1, acc[1][1], 0, 0, 0);
        __syncthreads();
    }
    if (pacc) {
        float* pbuf = pacc + (long long)blockIdx.z * Co * N;
#pragma unroll
        for (int nc = 0; nc < 2; ++nc) {
            int np = n0 + wc * 32 + nc * 16 + lm;
            if (np >= N) continue;
#pragma unroll
            for (int mr = 0; mr < 2; ++mr) {
                int cobase = m0 + wr * 32 + mr * 16 + lk * 4;
#pragma unroll
                for (int r = 0; r < 4; ++r)
                    pbuf[(long long)(cobase + r) * N + np] = acc[mr][nc][r];
            }
        }
    } else {
#pragma unroll
        for (int nc = 0; nc < 2; ++nc) {
            int np = n0 + wc * 32 + nc * 16 + lm;
            if (np >= N) continue;
            int ob = np / HoWo, op = np - ob * HoWo;
#pragma unroll
            for (int mr = 0; mr < 2; ++mr) {
                int cobase = m0 + wr * 32 + mr * 16 + lk * 4;
#pragma unroll
                for (int r = 0; r < 4; ++r) {
                    int co = cobase + r;
                    float v = fmaxf(acc[mr][nc][r] + effb[co], 0.f);
                    out[((long long)ob * Co + co) * HoWo + op] = __float2bfloat16(v);
                }
            }
        }
    }
}

// reduce conv5 K-split partials + bias + relu -> bf16 NCHW
__global__ void conv5_reduce(const float* __restrict__ pacc, const float* __restrict__ effb,
                             __hip_bfloat16* __restrict__ out) {
    int idx = blockIdx.x * 256 + threadIdx.x;
    if (idx >= 512 * 1568) return;
    int co = idx / 1568, n = idx - co * 1568;
    const long long st = (long long)512 * 1568;
    float s = pacc[(long long)co * 1568 + n] + pacc[st + (long long)co * 1568 + n] +
              pacc[2 * st + (long long)co * 1568 + n] + effb[co];
    s = fmaxf(s, 0.f);
    int b = n / 49, p = n - b * 49;
    out[((long long)b * 512 + co) * 49 + p] = __float2bfloat16(s);
}

// ---------------- BN stats (bf16 input), layers 2..5 ------------------------
__global__ void stats_partial(const __hip_bfloat16* __restrict__ y, float* __restrict__ part,
                              int B, int C, int HW, int S) {
    int c = blockIdx.x;
    int s = blockIdx.y;
    int tid = threadIdx.x;
    float sum = 0.f, sq = 0.f;
    for (int b = 0; b < B; ++b) {
        const __hip_bfloat16* yp = y + ((long long)b * C + c) * HW;
        for (int p = s * blockDim.x + tid; p < HW; p += S * blockDim.x) {
            float v = __bfloat162float(yp[p]);
            sum += v;
            sq = fmaf(v, v, sq);
        }
    }
    __shared__ float ls[256], lq[256];
    ls[tid] = sum; lq[tid] = sq;
    __syncthreads();
    for (int o = 128; o > 0; o >>= 1) {
        if (tid < o) { ls[tid] += ls[tid + o]; lq[tid] += lq[tid + o]; }
        __syncthreads();
    }
    if (tid == 0) {
        part[(c * S + s) * 2 + 0] = ls[0];
        part[(c * S + s) * 2 + 1] = lq[0];
    }
}

__global__ void stats_final(const float* __restrict__ part, const float* __restrict__ g,
                            const float* __restrict__ be, float* __restrict__ scale,
                            float* __restrict__ shift, int C, int S, float invN) {
    int c = blockIdx.x * blockDim.x + threadIdx.x;
    if (c >= C) return;
    float s = 0.f, q = 0.f;
    for (int i = 0; i < S; ++i) {
        s += part[(c * S + i) * 2 + 0];
        q += part[(c * S + i) * 2 + 1];
    }
    float m = s * invN;
    float v = q * invN - m * m;
    float inv = rsqrtf(v + BEPS);
    float sc = g[c] * inv;
    scale[c] = sc;
    shift[c] = be[c] - m * sc;
}

// ---------------- BN fold into next conv ------------------------------------
__global__ void fold_w_bf(const float* __restrict__ w, const float* __restrict__ scale,
                          ushort_t* __restrict__ wout, int Ci, int total) {
    int idx = blockIdx.x * blockDim.x + threadIdx.x;
    if (idx >= total) return;
    int ci = (idx / 9) % Ci;
    __hip_bfloat16 h = __float2bfloat16(w[idx] * scale[ci]);
    wout[idx] = *(ushort_t*)&h;
}

__global__ void fold_b(const float* __restrict__ w, const float* __restrict__ shift,
                       const float* __restrict__ bias, float* __restrict__ effb,
                       int Co, int Ci) {
    int co = blockIdx.x * blockDim.x + threadIdx.x;
    if (co >= Co) return;
    float acc = bias[co];
    const float* wr = w + (long long)co * Ci * 9;
    for (int ci = 0; ci < Ci; ++ci) {
        float sh = shift[ci];
#pragma unroll
        for (int t = 0; t < 9; ++t) acc = fmaf(wr[ci * 9 + t], sh, acc);
    }
    effb[co] = acc;
}

// ---------------- BN apply conv5 out (bf16) -> xT fp32 [k][32] --------------
__global__ void bn_apply_t(const __hip_bfloat16* __restrict__ y, const float* __restrict__ scale,
                           const float* __restrict__ shift, float* __restrict__ xT) {
    int idx = blockIdx.x * blockDim.x + threadIdx.x;
    if (idx >= 802816) return;
    int k = idx >> 5, b = idx & 31;
    int c = k / 49;
    xT[idx] = fmaf(__bfloat162float(y[(long long)b * 25088 + k]), scale[c], shift[c]);
}

// ---------------- fc1 split-K GEMM ------------------------------------------
__global__ __launch_bounds__(256) void fc1_gemm(const float* __restrict__ xT,
                                                const float* __restrict__ w,
                                                float* __restrict__ part) {
    const int K = 25088;
    __shared__ __align__(16) float As[16][64];
    __shared__ __align__(16) float Bs[16][32];
    const int tid = threadIdx.x;
    const int m0 = blockIdx.y * 64;
    const int kbeg = blockIdx.x * FC1_KC;
    const int cA = tid >> 2;
    const int kqA = (tid & 3) * 4;
    const int kkB = tid >> 5;
    const int bB = tid & 31;
    const int tm = tid >> 4;
    const int tn = tid & 15;

    const int mrow = m0 + cA;
    const bool mvalid = (mrow < 1000);
    const float* wrow = w + (long long)mrow * K + kbeg + kqA;

    float acc[4][2] = {};
    for (int k0 = 0; k0 < FC1_KC; k0 += 16) {
        float4 av = mvalid ? *(const float4*)(wrow + k0)
                           : make_float4(0.f, 0.f, 0.f, 0.f);
        As[kqA + 0][cA] = av.x;
        As[kqA + 1][cA] = av.y;
        As[kqA + 2][cA] = av.z;
        As[kqA + 3][cA] = av.w;
#pragma unroll
        for (int e = 0; e < 2; ++e) {
            int kk = kkB + e * 8;
            Bs[kk][bB] = xT[(kbeg + k0 + kk) * 32 + bB];
        }
        __syncthreads();
#pragma unroll
        for (int kk = 0; kk < 16; ++kk) {
            float4 a = *(const float4*)&As[kk][tm * 4];
            float b0 = Bs[kk][tn * 2 + 0];
            float b1 = Bs[kk][tn * 2 + 1];
            float a4[4] = {a.x, a.y, a.z, a.w};
#pragma unroll
            for (int mi = 0; mi < 4; ++mi) {
                acc[mi][0] = fmaf(a4[mi], b0, acc[mi][0]);
                acc[mi][1] = fmaf(a4[mi], b1, acc[mi][1]);
            }
        }
        __syncthreads();
    }
    float* pb = part + ((long long)blockIdx.y * FC1_KS + blockIdx.x) * 2048;
#pragma unroll
    for (int mi = 0; mi < 4; ++mi) {
        pb[(tm * 4 + mi) * 32 + tn * 2 + 0] = acc[mi][0];
        pb[(tm * 4 + mi) * 32 + tn * 2 + 1] = acc[mi][1];
    }
}

__global__ void fc1_reduce(const float* __restrict__ part, const float* __restrict__ bias,
                           float* __restrict__ z) {
    int idx = blockIdx.x * blockDim.x + threadIdx.x;
    if (idx >= 32000) return;
    int o = idx >> 5, b = idx & 31;
    int mt = o >> 6, mr = o & 63;
    const float* p = part + ((long long)mt * FC1_KS) * 2048 + mr * 32 + b;
    float s0 = 0.f, s1 = 0.f;
    int ks = 0;
    for (; ks + 1 < FC1_KS; ks += 2) {
        s0 += p[(long long)ks * 2048];
        s1 += p[(long long)(ks + 1) * 2048];
    }
    for (; ks < FC1_KS; ++ks) s0 += p[(long long)ks * 2048];
    z[b * 1000 + o] = fmaxf(s0 + s1 + bias[o], 0.f);
}

// ---------------- fc2 -------------------------------------------------------
__global__ __launch_bounds__(256) void fc2_v2(const float* __restrict__ z,
                                              const float* __restrict__ w,
                                              const float* __restrict__ bias,
                                              float* __restrict__ ys) {
    int gid = blockIdx.x * 4 + (threadIdx.x >> 6);
    int lane = threadIdx.x & 63;
    if (gid >= 960) return;
    int b = gid / 30, o = gid - b * 30;
    const float* zr = z + (long long)b * 1000;
    const float* wr = w + (long long)o * 1000;
    float acc = 0.f;
    for (int k = lane; k < 1000; k += 64) acc = fmaf(zr[k], wr[k], acc);
    for (int off = 32; off > 0; off >>= 1) acc += __shfl_down(acc, off, 64);
    if (lane == 0) ys[gid] = acc + bias[o];
}

// ---------------- spline coefficients -> float4 per segment -----------------
__global__ void spline_coeff(const float* __restrict__ ysraw, const float* __restrict__ matrix,
                             float4* __restrict__ coef) {
    int r = threadIdx.x;
    if (r >= 96) return;
    const float h = 1.0f / 9.0f;
    float ya[10];
    int b = r / 3, ch = r % 3;
#pragma unroll
    for (int j = 0; j < 10; ++j)
        ya[j] = ysraw[b * 30 + ch * 10 + j] / 100.0f + (float)j / 9.0f;
    float M[10];
#pragma unroll
    for (int i = 0; i < 10; ++i) {
        float acc = 0.f;
#pragma unroll
        for (int j = 0; j < 10; ++j) acc = fmaf(matrix[i * 10 + j], ya[j], acc);
        M[i] = acc;
    }
#pragma unroll
    for (int k = 0; k < 9; ++k) {
        float a = (M[k + 1] - M[k]) / (6.0f * h);
        float bb = M[k] * 0.5f;
        float cc = (ya[k + 1] - ya[k]) / h - (M[k + 1] + 2.0f * M[k]) * (h / 6.0f);
        float dd = ya[k];
        coef[r * 9 + k] = make_float4(a, bb, cc, dd);
    }
}

// ---------------- spline eval on the image (float4) -------------------------
__global__ void eval_img4(const float4* __restrict__ batch4, const float4* __restrict__ coef,
                          float4* __restrict__ out4) {
    int idx = blockIdx.x * blockDim.x + threadIdx.x;
    if (idx >= 1572864) return;
    int plane = idx >> 14;
    float4 xv4 = batch4[idx];
    const float h = 1.0f / 9.0f;
    float xin[4] = {xv4.x, xv4.y, xv4.z, xv4.w};
    float xout[4];
#pragma unroll
    for (int e = 0; e < 4; ++e) {
        float xv = xin[e];
        int xi = (int)floorf(xv / h);
        xi = min(max(xi, 0), 8);
        float xf = xv - (float)xi * h;
        float4 cf = coef[plane * 9 + xi];
        xout[e] = fmaf(fmaf(fmaf(cf.x, xf, cf.y), xf, cf.z), xf, cf.w);
    }
    out4[idx] = make_float4(xout[0], xout[1], xout[2], xout[3]);
}

// ---------------- spline eval on the 255-value table ------------------------
__global__ void eval_tab(const float4* __restrict__ coef, float* __restrict__ out, int total) {
    int idx = blockIdx.x * blockDim.x + threadIdx.x;
    if (idx >= total) return;
    int plane = idx / 255;
    int j = idx % 255;
    float xv = (float)j / 255.0f;
    const float h = 1.0f / 9.0f;
    int xi = (int)floorf(xv / h);
    xi = min(max(xi, 0), 8);
    float xf = xv - (float)xi * h;
    float4 cf = coef[plane * 9 + xi];
    out[idx] = fmaf(fmaf(fmaf(cf.x, xf, cf.y), xf, cf.z), xf, cf.w);
}

extern "C" void kernel_launch(void* const* d_in, const int* in_sizes, int n_in,
                              void* d_out, int out_size, void* d_ws, size_t ws_size,
                              hipStream_t stream) {
    const int B = 32;
    const float* batch = (const float*)d_in[0];
    const float* cw[5] = {(const float*)d_in[1], (const float*)d_in[5], (const float*)d_in[9],
                          (const float*)d_in[13], (const float*)d_in[17]};
    const float* cb[5] = {(const float*)d_in[2], (const float*)d_in[6], (const float*)d_in[10],
                          (const float*)d_in[14], (const float*)d_in[18]};
    const float* bg[5] = {(const float*)d_in[3], (const float*)d_in[7], (const float*)d_in[11],
                          (const float*)d_in[15], (const float*)d_in[19]};
    const float* bb[5] = {(const float*)d_in[4], (const float*)d_in[8], (const float*)d_in[12],
                          (const float*)d_in[16], (const float*)d_in[20]};
    const float* l1w = (const float*)d_in[21];
    const float* l1b = (const float*)d_in[22];
    const float* l2w = (const float*)d_in[23];
    const float* l2b = (const float*)d_in[24];
    const float* matrix = (const float*)d_in[25];

    float* f = (float*)d_ws;
    const size_t A_F = 8258048;
    const size_t Bq_F = 4064256;
    const size_t W_F = 589824;
    __hip_bfloat16* bufA_bf = (__hip_bfloat16*)f;
    __hip_bfloat16* bufB_bf = (__hip_bfloat16*)(f + A_F);
    ushort_t* Wf_bf = (ushort_t*)(f + A_F + Bq_F);
    float* effb  = f + A_F + Bq_F + W_F;   // 512
    float* scale = effb + 512;             // 512
    float* shift = scale + 512;            // 512
    float* part  = shift + 512;            // 8192
    float* part2 = part + 8192;            // 64*2048 = 131,072 (transposed)
    float* x5    = part2 + 131072;         // 802,816
    float* fc1p  = x5 + 802816;            // 3,211,264 (shared with conv5 pacc)
    float* z1    = fc1p + 3211264;         // 32,000
    float* ysb   = z1 + 32000;             // 960
    float4* coef = (float4*)(ysb + 960);   // 96*9 float4

    const int Ci[5] = {3, 32, 64, 128, 256};
    const int Co[5] = {32, 64, 128, 256, 512};
    const int Hi[5] = {256, 127, 63, 31, 15};
    const int Ho[5] = {127, 63, 31, 15, 7};
    const int S = 8;

    __hip_bfloat16* bufs[2] = {bufA_bf, bufB_bf};

    // layer 1: direct conv + fused stats
    {
        conv1_direct<<<C1NB, 256, 0, stream>>>(batch, cw[0], cb[0], bufA_bf, part2);
        conv1_stats_final<<<32, 256, 0, stream>>>(part2, bg[0], bb[0], scale, shift, C1NB,
                                                  1.0f / (32 * 16129));
    }

    // layers 2..5: MFMA bf16
    const __hip_bfloat16* cur = bufA_bf;
    for (int l = 1; l < 5; ++l) {
        __hip_bfloat16* outb = bufs[l % 2];
        int K = Ci[l] * 9;
        int wtotal = Co[l] * K;
        fold_w_bf<<<(wtotal + 255) / 256, 256, 0, stream>>>(cw[l], scale, Wf_bf, Ci[l], wtotal);
        fold_b<<<(Co[l] + 63) / 64, 64, 0, stream>>>(cw[l], shift, cb[l], effb, Co[l], Ci[l]);
        int N = B * Ho[l] * Ho[l];
        if (l < 4) {
            dim3 grid((N + 63) / 64, Co[l] / 64, 1);
            conv_mfma<<<grid, 256, 0, stream>>>(cur, Wf_bf, effb, outb, nullptr, B, Ci[l],
                                                Hi[l], Hi[l], Co[l], Ho[l], Ho[l], K, K);
        } else {
            dim3 grid((N + 63) / 64, Co[l] / 64, 3);
            conv_mfma<<<grid, 256, 0, stream>>>(cur, Wf_bf, effb, nullptr, fc1p, B, Ci[l],
                                                Hi[l], Hi[l], Co[l], Ho[l], Ho[l], K, 768);
            conv5_reduce<<<(512 * 1568 + 255) / 256, 256, 0, stream>>>(fc1p, effb, outb);
        }
        stats_partial<<<dim3(Co[l], S), 256, 0, stream>>>(outb, part, B, Co[l],
                                                          Ho[l] * Ho[l], S);
        stats_final<<<(Co[l] + 63) / 64, 64, 0, stream>>>(part, bg[l], bb[l], scale, shift,
                                                          Co[l], S, 1.0f / (B * Ho[l] * Ho[l]));
        cur = outb;
    }

    bn_apply_t<<<(802816 + 255) / 256, 256, 0, stream>>>(cur, scale, shift, x5);
    {
        dim3 grid(FC1_KS, 16);
        fc1_gemm<<<grid, 256, 0, stream>>>(x5, l1w, fc1p);
    }
    fc1_reduce<<<(32000 + 255) / 256, 256, 0, stream>>>(fc1p, l1b, z1);
    fc2_v2<<<240, 256, 0, stream>>>(z1, l2w, l2b, ysb);
    spline_coeff<<<1, 96, 0, stream>>>(ysb, matrix, coef);

    float* out = (float*)d_out;
    eval_img4<<<(1572864 + 255) / 256, 256, 0, stream>>>((const float4*)batch, coef,
                                                         (float4*)out);
    eval_tab<<<(96 * 255 + 255) / 256, 256, 0, stream>>>(coef, out + 6291456, 96 * 255);
}